// Round 9
// baseline (4228.386 us; speedup 1.0000x reference)
//
#include <hip/hip_runtime.h>
#include <math.h>

// ---------------------------------------------------------------------------
// GCN 3-layer forward for MI355X.
// R5: tiled GEMM (733->101us). R7: CSR gather agg (1161->586). R8: counting-
//   sort CSR build, 1 atomic/edge (586->439).
// R9: GEMM was latency-bound (VALUBusy 27%, HBM 9.5%, occ 34%: scalar staging
//   loads + barrier every tile). Fix: float4 staging + REGISTER prefetch of
//   tile t+1 during compute of tile t (single LDS buffer, 17KB, keeps 8
//   blocks/CU eligibility; dbuf would cap at 4).
// ---------------------------------------------------------------------------

__global__ void k_cnt(const int* __restrict__ dst, int* __restrict__ cnt,
                      int* __restrict__ pos, int E) {
    int e = blockIdx.x * blockDim.x + threadIdx.x;
    if (e < E) pos[e] = atomicAdd(&cnt[dst[e]], 1);
}

// ---- exclusive scan over cnt[N] -> rowptr, 3 kernels ----
__global__ void k_scan1(const int* __restrict__ cnt, int* __restrict__ excl,
                        int* __restrict__ bsum, int n) {
    __shared__ int sm[256];
    int tid = threadIdx.x;
    int i = blockIdx.x * 256 + tid;
    int v = (i < n) ? cnt[i] : 0;
    sm[tid] = v;
    __syncthreads();
    for (int off = 1; off < 256; off <<= 1) {
        int t = (tid >= off) ? sm[tid - off] : 0;
        __syncthreads();
        sm[tid] += t;
        __syncthreads();
    }
    if (i < n) excl[i] = sm[tid] - v;
    if (tid == 255) bsum[blockIdx.x] = sm[255];
}

__global__ void k_scan2(const int* __restrict__ bsum, int* __restrict__ boff, int nb) {
    __shared__ int sm[512];
    int tid = threadIdx.x;
    int v = (tid < nb) ? bsum[tid] : 0;
    sm[tid] = v;
    __syncthreads();
    for (int off = 1; off < 512; off <<= 1) {
        int t = (tid >= off) ? sm[tid - off] : 0;
        __syncthreads();
        sm[tid] += t;
        __syncthreads();
    }
    boff[tid] = sm[tid] - v;   // exclusive
}

__global__ void k_scan3(int* __restrict__ rowptr, const int* __restrict__ boff,
                        int n, int E) {
    int i = blockIdx.x * blockDim.x + threadIdx.x;
    if (i < n) rowptr[i] += boff[i >> 8];
    if (i == 0) rowptr[n] = E;
}

// Place edges into dst-grouped slots (NO atomic): 8B packed {src, ew}.
__global__ void k_place(const int* __restrict__ src, const int* __restrict__ dst,
                        const float* __restrict__ ew, const int* __restrict__ rowptr,
                        const int* __restrict__ pos, unsigned long long* __restrict__ pairP,
                        int E) {
    int e = blockIdx.x * blockDim.x + threadIdx.x;
    if (e < E) {
        int d = dst[e];
        int p = rowptr[d] + pos[e];
        unsigned long long pk = (unsigned long long)__float_as_uint(ew[e]) << 32
                              | (unsigned int)src[e];
        pairP[p] = pk;
    }
}

// Per-node: dis = rsqrt(1 + sum ew) from CSR pairs (payload = ew here).
__global__ void k_deg_dis(const unsigned long long* __restrict__ pairP,
                          const int* __restrict__ rowptr, float* __restrict__ dis, int n) {
    int i = blockIdx.x * blockDim.x + threadIdx.x;
    if (i >= n) return;
    int a = rowptr[i], b = rowptr[i + 1];
    float s = 1.0f;   // self-loop weight
    for (int p = a; p < b; ++p)
        s += __uint_as_float((unsigned int)(pairP[p] >> 32));
    dis[i] = (s > 0.f) ? rsqrtf(s) : 0.f;
}

// Per-node: rewrite pair payload ew -> nrm = dis[s]*ew*dis[d] (in place).
__global__ void k_norm_csr(unsigned long long* __restrict__ pairP,
                           const int* __restrict__ rowptr,
                           const float* __restrict__ dis, int n) {
    int i = blockIdx.x * blockDim.x + threadIdx.x;
    if (i >= n) return;
    int a = rowptr[i], b = rowptr[i + 1];
    float dd = dis[i];
    for (int p = a; p < b; ++p) {
        unsigned long long pk = pairP[p];
        int s = (int)(unsigned int)pk;
        float w = __uint_as_float((unsigned int)(pk >> 32));
        float nrm = dis[s] * w * dd;
        pairP[p] = ((unsigned long long)__float_as_uint(nrm) << 32) | (unsigned int)s;
    }
}

// Tiled GEMM: Hout = act(X) @ W  (BM64 x BN64 x BK32, 4x4 reg tile).
// R9: float4 staging + register prefetch of next tile during compute.
template<int K, int NOUT, bool RELU_IN>
__global__ __launch_bounds__(256) void k_gemm(
    const float* __restrict__ X, const float* __restrict__ W,
    float* __restrict__ Hout, int nrows)
{
    constexpr int BM = 64, BN = 64, BK = 32;
    constexpr int T  = K / BK;
    __shared__ float As[BK][BM + 4];   // As[k][m]; stride 68 words keeps b128 align
    __shared__ float Bs[BK][BN + 4];

    const int tid = (int)threadIdx.x;
    const int tx  = tid & 15;          // cols tx*4..+3
    const int ty  = tid >> 4;          // rows ty*4..+3
    const int r0  = (int)blockIdx.x * BM;

    // staging coords
    const int ar = tid >> 3;           // 0..31 (A row piece; +32 on 2nd iter)
    const int aq = tid & 7;            // A float4 idx within BK (8 per row)
    const int bk = tid >> 4;           // 0..15 (W row piece; +16 on 2nd iter)
    const int bc = tid & 15;           // W float4 col idx (16 per row)

    float4 ra[2], rb[2];

    auto load_tile = [&](int k0) {
#pragma unroll
        for (int i = 0; i < 2; ++i) {
            int row = r0 + ar + i * 32;
            float4 v = make_float4(0.f, 0.f, 0.f, 0.f);
            if (row < nrows)
                v = *(const float4*)&X[(size_t)row * K + k0 + aq * 4];
            if (RELU_IN) {
                v.x = fmaxf(v.x, 0.f); v.y = fmaxf(v.y, 0.f);
                v.z = fmaxf(v.z, 0.f); v.w = fmaxf(v.w, 0.f);
            }
            ra[i] = v;
        }
#pragma unroll
        for (int i = 0; i < 2; ++i) {
            int kk = bk + i * 16;
            float4 v = make_float4(0.f, 0.f, 0.f, 0.f);
            if (bc * 4 + 3 < NOUT)
                v = *(const float4*)&W[(size_t)(k0 + kk) * NOUT + bc * 4];
            rb[i] = v;
        }
    };
    auto store_tile = [&]() {
#pragma unroll
        for (int i = 0; i < 2; ++i) {
            int r = ar + i * 32;
            As[aq * 4 + 0][r] = ra[i].x;
            As[aq * 4 + 1][r] = ra[i].y;
            As[aq * 4 + 2][r] = ra[i].z;
            As[aq * 4 + 3][r] = ra[i].w;
        }
#pragma unroll
        for (int i = 0; i < 2; ++i)
            *(float4*)&Bs[bk + i * 16][bc * 4] = rb[i];
    };

    float acc[4][4] = {};

    load_tile(0);
    store_tile();
    __syncthreads();

#pragma unroll
    for (int t = 0; t < T; ++t) {
        if (t + 1 < T) load_tile((t + 1) * BK);   // in flight during compute
#pragma unroll
        for (int kk = 0; kk < BK; ++kk) {
            float4 a = *(const float4*)&As[kk][ty * 4];
            float4 b = *(const float4*)&Bs[kk][tx * 4];
            acc[0][0] += a.x * b.x; acc[0][1] += a.x * b.y; acc[0][2] += a.x * b.z; acc[0][3] += a.x * b.w;
            acc[1][0] += a.y * b.x; acc[1][1] += a.y * b.y; acc[1][2] += a.y * b.z; acc[1][3] += a.y * b.w;
            acc[2][0] += a.z * b.x; acc[2][1] += a.z * b.y; acc[2][2] += a.z * b.z; acc[2][3] += a.z * b.w;
            acc[3][0] += a.w * b.x; acc[3][1] += a.w * b.y; acc[3][2] += a.w * b.z; acc[3][3] += a.w * b.w;
        }
        if (t + 1 < T) {
            __syncthreads();       // all reads of current tile done
            store_tile();
            __syncthreads();       // next tile visible
        }
    }

    if (tx * 4 + 3 < NOUT) {
#pragma unroll
        for (int i = 0; i < 4; ++i) {
            int row = r0 + ty * 4 + i;
            if (row < nrows)
                *(float4*)&Hout[(size_t)row * NOUT + tx * 4] =
                    make_float4(acc[i][0], acc[i][1], acc[i][2], acc[i][3]);
        }
    }
}

// Gather aggregation: one wave per node, lane = feature. No atomics.
// out[row] = h[row]*dis[row]^2 + bias + sum_j h[src_j] * nrm_j  (packed pairs)
template<int F>
__global__ __launch_bounds__(256) void k_node_agg(
    const float* __restrict__ h, const float* __restrict__ dis,
    const float* __restrict__ bias, const int* __restrict__ rowptr,
    const unsigned long long* __restrict__ pairP,
    float* __restrict__ out, int n)
{
    const int lane = threadIdx.x & 63;
    int row = (int)((blockIdx.x * blockDim.x + threadIdx.x) >> 6);
    if (row >= n) return;
    row = __builtin_amdgcn_readfirstlane(row);   // wave-uniform -> SGPR addrs

    const int a = rowptr[row], b = rowptr[row + 1];
    float d  = dis[row];
    float dd = d * d;
    float sum = 0.f;
    if (lane < F) sum = h[(size_t)row * F + lane] * dd + bias[lane];

    int j = a;
    for (; j + 4 <= b; j += 4) {
        unsigned long long p0 = pairP[j],     p1 = pairP[j + 1];
        unsigned long long p2 = pairP[j + 2], p3 = pairP[j + 3];
        int   s0 = (int)(unsigned int)p0, s1 = (int)(unsigned int)p1;
        int   s2 = (int)(unsigned int)p2, s3 = (int)(unsigned int)p3;
        float w0 = __uint_as_float((unsigned int)(p0 >> 32));
        float w1 = __uint_as_float((unsigned int)(p1 >> 32));
        float w2 = __uint_as_float((unsigned int)(p2 >> 32));
        float w3 = __uint_as_float((unsigned int)(p3 >> 32));
        if (lane < F) {
            sum += h[(size_t)s0 * F + lane] * w0;
            sum += h[(size_t)s1 * F + lane] * w1;
            sum += h[(size_t)s2 * F + lane] * w2;
            sum += h[(size_t)s3 * F + lane] * w3;
        }
    }
    for (; j < b; ++j) {
        unsigned long long p = pairP[j];
        int s = (int)(unsigned int)p;
        float w = __uint_as_float((unsigned int)(p >> 32));
        if (lane < F) sum += h[(size_t)s * F + lane] * w;
    }
    if (lane < F) out[(size_t)row * F + lane] = sum;
}

// In-place log_softmax over C columns; one wave per row.
template<int C>
__global__ void k_logsoftmax(float* __restrict__ io, int n) {
    const int lane = threadIdx.x & 63;
    int row = (int)((blockIdx.x * blockDim.x + threadIdx.x) >> 6);
    if (row >= n) return;
    float v = (lane < C) ? io[(size_t)row * C + lane] : -INFINITY;
    float m = v;
#pragma unroll
    for (int off = 32; off; off >>= 1) m = fmaxf(m, __shfl_xor(m, off));
    float e = (lane < C) ? expf(v - m) : 0.f;
    float s = e;
#pragma unroll
    for (int off = 32; off; off >>= 1) s += __shfl_xor(s, off);
    float ls = logf(s);
    if (lane < C) io[(size_t)row * C + lane] = v - m - ls;
}

extern "C" void kernel_launch(void* const* d_in, const int* in_sizes, int n_in,
                              void* d_out, int out_size, void* d_ws, size_t ws_size,
                              hipStream_t stream) {
    const float* x  = (const float*)d_in[0];
    const int*   ei = (const int*)  d_in[1];
    const float* ew = (const float*)d_in[2];
    const float* W0 = (const float*)d_in[3];
    const float* b0 = (const float*)d_in[4];
    const float* W1 = (const float*)d_in[5];
    const float* b1 = (const float*)d_in[6];
    const float* W2 = (const float*)d_in[7];
    const float* b2 = (const float*)d_in[8];

    const int E   = in_sizes[2];            // 1600000
    const int H   = in_sizes[4];            // 64
    const int Fin = in_sizes[3] / H;        // 256
    const int N   = in_sizes[0] / Fin;      // 100000
    (void)n_in; (void)out_size; (void)ws_size;

    const int* srcv = ei;                   // edge_index[0]
    const int* dstv = ei + E;               // edge_index[1]

    // ---- workspace layout (64-float = 256B aligned chunks; 8B-safe) ----
    float* ws = (float*)d_ws;
    size_t o = 0;
    auto alloc = [&](size_t cnt) { size_t p = o; o += (cnt + 63) & ~(size_t)63; return p; };
    float* dis   = ws + alloc(N);
    float* bufA  = ws + alloc((size_t)N * 64);       // h
    float* bufB  = ws + alloc((size_t)N * 64);       // agg
    unsigned long long* pairP = (unsigned long long*)(ws + alloc((size_t)E * 2));
    int*   rowptr= (int*)(ws + alloc(N + 1));
    int*   cnt   = (int*)(ws + alloc(N));
    int*   pos   = (int*)(ws + alloc(E));
    int*   bsum  = (int*)(ws + alloc(512));
    int*   boff  = (int*)(ws + alloc(512));
    float* outf  = (float*)d_out;                    // N*40

    const int TB = 256;
    const int nb1 = (N + 255) / 256;                 // scan blocks (391 <= 512)

    // ---- CSR build (counting sort, 1 atomic/edge total) ----
    hipMemsetAsync(cnt, 0, (size_t)N * sizeof(int), stream);
    k_cnt  <<<(E + TB - 1) / TB, TB, 0, stream>>>(dstv, cnt, pos, E);
    k_scan1<<<nb1, 256, 0, stream>>>(cnt, rowptr, bsum, N);
    k_scan2<<<1, 512, 0, stream>>>(bsum, boff, nb1);
    k_scan3<<<(N + TB - 1) / TB, TB, 0, stream>>>(rowptr, boff, N, E);
    k_place<<<(E + TB - 1) / TB, TB, 0, stream>>>(srcv, dstv, ew, rowptr, pos, pairP, E);
    k_deg_dis <<<(N + TB - 1) / TB, TB, 0, stream>>>(pairP, rowptr, dis, N);
    k_norm_csr<<<(N + TB - 1) / TB, TB, 0, stream>>>(pairP, rowptr, dis, N);

    const int gemmGrid = (N + 63) / 64;
    const int aggGrid  = (N * 64 + TB - 1) / TB;     // one wave per node

    // ---- layer 0: x(256) -> 64 ----
    k_gemm<256, 64, false><<<gemmGrid, TB, 0, stream>>>(x, W0, bufA, N);
    k_node_agg<64><<<aggGrid, TB, 0, stream>>>(bufA, dis, b0, rowptr, pairP, bufB, N);

    // ---- layer 1: 64 -> 64 (relu on load) ----
    k_gemm<64, 64, true><<<gemmGrid, TB, 0, stream>>>(bufB, W1, bufA, N);
    k_node_agg<64><<<aggGrid, TB, 0, stream>>>(bufA, dis, b1, rowptr, pairP, bufB, N);

    // ---- layer 2: 64 -> 40, aggregate straight into d_out ----
    k_gemm<64, 40, true><<<gemmGrid, TB, 0, stream>>>(bufB, W2, bufA, N);
    k_node_agg<40><<<aggGrid, TB, 0, stream>>>(bufA, dis, b2, rowptr, pairP, outf, N);

    // ---- log_softmax in-place on d_out ----
    k_logsoftmax<40><<<(N * 64 + TB - 1) / TB, TB, 0, stream>>>(outf, N);
}

// Round 11
// 420.971 us; speedup vs baseline: 10.0444x; 10.0444x over previous
//
#include <hip/hip_runtime.h>
#include <math.h>

// ---------------------------------------------------------------------------
// GCN 3-layer forward for MI355X.
// R5: tiled GEMM (733->101us). R7: CSR gather agg (1161->586). R8: counting-
//   sort CSR build, 1 atomic/edge (586->439).
// R9 FAILED: full-unroll T-loop + lambda prefetch -> VGPR 256 + 7.9GB scratch
//   spill traffic. Lesson: unrolling the K-tile loop explodes the live set.
// R10 FAILED: compile error (float4 load through float* without cast).
// R11: same reg-prefetch schedule, fixed: explicit float4 casts, unroll 1,
//   named regs, clamped row addrs.
// ---------------------------------------------------------------------------

__global__ void k_cnt(const int* __restrict__ dst, int* __restrict__ cnt,
                      int* __restrict__ pos, int E) {
    int e = blockIdx.x * blockDim.x + threadIdx.x;
    if (e < E) pos[e] = atomicAdd(&cnt[dst[e]], 1);
}

// ---- exclusive scan over cnt[N] -> rowptr, 3 kernels ----
__global__ void k_scan1(const int* __restrict__ cnt, int* __restrict__ excl,
                        int* __restrict__ bsum, int n) {
    __shared__ int sm[256];
    int tid = threadIdx.x;
    int i = blockIdx.x * 256 + tid;
    int v = (i < n) ? cnt[i] : 0;
    sm[tid] = v;
    __syncthreads();
    for (int off = 1; off < 256; off <<= 1) {
        int t = (tid >= off) ? sm[tid - off] : 0;
        __syncthreads();
        sm[tid] += t;
        __syncthreads();
    }
    if (i < n) excl[i] = sm[tid] - v;
    if (tid == 255) bsum[blockIdx.x] = sm[255];
}

__global__ void k_scan2(const int* __restrict__ bsum, int* __restrict__ boff, int nb) {
    __shared__ int sm[512];
    int tid = threadIdx.x;
    int v = (tid < nb) ? bsum[tid] : 0;
    sm[tid] = v;
    __syncthreads();
    for (int off = 1; off < 512; off <<= 1) {
        int t = (tid >= off) ? sm[tid - off] : 0;
        __syncthreads();
        sm[tid] += t;
        __syncthreads();
    }
    boff[tid] = sm[tid] - v;   // exclusive
}

__global__ void k_scan3(int* __restrict__ rowptr, const int* __restrict__ boff,
                        int n, int E) {
    int i = blockIdx.x * blockDim.x + threadIdx.x;
    if (i < n) rowptr[i] += boff[i >> 8];
    if (i == 0) rowptr[n] = E;
}

// Place edges into dst-grouped slots (NO atomic): 8B packed {src, ew}.
__global__ void k_place(const int* __restrict__ src, const int* __restrict__ dst,
                        const float* __restrict__ ew, const int* __restrict__ rowptr,
                        const int* __restrict__ pos, unsigned long long* __restrict__ pairP,
                        int E) {
    int e = blockIdx.x * blockDim.x + threadIdx.x;
    if (e < E) {
        int d = dst[e];
        int p = rowptr[d] + pos[e];
        unsigned long long pk = (unsigned long long)__float_as_uint(ew[e]) << 32
                              | (unsigned int)src[e];
        pairP[p] = pk;
    }
}

// Per-node: dis = rsqrt(1 + sum ew) from CSR pairs (payload = ew here).
__global__ void k_deg_dis(const unsigned long long* __restrict__ pairP,
                          const int* __restrict__ rowptr, float* __restrict__ dis, int n) {
    int i = blockIdx.x * blockDim.x + threadIdx.x;
    if (i >= n) return;
    int a = rowptr[i], b = rowptr[i + 1];
    float s = 1.0f;   // self-loop weight
    for (int p = a; p < b; ++p)
        s += __uint_as_float((unsigned int)(pairP[p] >> 32));
    dis[i] = (s > 0.f) ? rsqrtf(s) : 0.f;
}

// Per-node: rewrite pair payload ew -> nrm = dis[s]*ew*dis[d] (in place).
__global__ void k_norm_csr(unsigned long long* __restrict__ pairP,
                           const int* __restrict__ rowptr,
                           const float* __restrict__ dis, int n) {
    int i = blockIdx.x * blockDim.x + threadIdx.x;
    if (i >= n) return;
    int a = rowptr[i], b = rowptr[i + 1];
    float dd = dis[i];
    for (int p = a; p < b; ++p) {
        unsigned long long pk = pairP[p];
        int s = (int)(unsigned int)pk;
        float w = __uint_as_float((unsigned int)(pk >> 32));
        float nrm = dis[s] * w * dd;
        pairP[p] = ((unsigned long long)__float_as_uint(nrm) << 32) | (unsigned int)s;
    }
}

// Tiled GEMM: Hout = act(X) @ W  (BM64 x BN64 x BK32, 4x4 reg tile).
// R11: float4 staging + register prefetch; T-loop NOT unrolled (unroll 1).
template<int K, int NOUT, bool RELU_IN>
__global__ __launch_bounds__(256) void k_gemm(
    const float* __restrict__ X, const float* __restrict__ W,
    float* __restrict__ Hout, int nrows)
{
    constexpr int BM = 64, BN = 64, BK = 32;
    constexpr int T  = K / BK;
    __shared__ float As[BK][BM + 4];   // As[k][m]
    __shared__ float Bs[BK][BN + 4];

    const int tid = (int)threadIdx.x;
    const int tx  = tid & 15;          // cols tx*4..+3
    const int ty  = tid >> 4;          // rows ty*4..+3
    const int r0  = (int)blockIdx.x * BM;

    // staging coords: A = 64 rows x 8 float4 (512 f4, 2/thread)
    //                 B = 32 k-rows x 16 float4 (512 f4, 2/thread)
    const int ar = tid >> 3;           // 0..31, rows ar and ar+32
    const int aq = tid & 7;            // float4 index in k-dir
    const int bk = tid >> 4;           // 0..15, k-rows bk and bk+16
    const int bc = tid & 15;           // float4 index in n-dir

    // branch-free clamped A row addresses (dup rows never written back)
    const int rowA0 = min(r0 + ar,      nrows - 1);
    const int rowA1 = min(r0 + ar + 32, nrows - 1);
    const float* pA0 = X + (size_t)rowA0 * K + aq * 4;
    const float* pA1 = X + (size_t)rowA1 * K + aq * 4;
    const bool wok = (bc * 4 + 3 < NOUT);   // W guard (NOUT=40 case)
    const float* pB0 = W + (size_t)bk * NOUT + bc * 4;
    const float* pB1 = W + (size_t)(bk + 16) * NOUT + bc * 4;
    const float4 z4 = make_float4(0.f, 0.f, 0.f, 0.f);

    float4 ra0, ra1, rb0, rb1;

    // prologue: tile 0
    ra0 = *(const float4*)pA0;
    ra1 = *(const float4*)pA1;
    rb0 = wok ? *(const float4*)pB0 : z4;
    rb1 = wok ? *(const float4*)pB1 : z4;

    float acc[4][4] = {};

#pragma unroll 1
    for (int t = 0; t < T; ++t) {
        // ---- store staged regs to LDS ----
        if (RELU_IN) {
            ra0.x = fmaxf(ra0.x, 0.f); ra0.y = fmaxf(ra0.y, 0.f);
            ra0.z = fmaxf(ra0.z, 0.f); ra0.w = fmaxf(ra0.w, 0.f);
            ra1.x = fmaxf(ra1.x, 0.f); ra1.y = fmaxf(ra1.y, 0.f);
            ra1.z = fmaxf(ra1.z, 0.f); ra1.w = fmaxf(ra1.w, 0.f);
        }
        As[aq * 4 + 0][ar]      = ra0.x;
        As[aq * 4 + 1][ar]      = ra0.y;
        As[aq * 4 + 2][ar]      = ra0.z;
        As[aq * 4 + 3][ar]      = ra0.w;
        As[aq * 4 + 0][ar + 32] = ra1.x;
        As[aq * 4 + 1][ar + 32] = ra1.y;
        As[aq * 4 + 2][ar + 32] = ra1.z;
        As[aq * 4 + 3][ar + 32] = ra1.w;
        *(float4*)&Bs[bk][bc * 4]      = rb0;
        *(float4*)&Bs[bk + 16][bc * 4] = rb1;
        __syncthreads();

        // ---- issue prefetch for tile t+1 (in flight during compute) ----
        if (t + 1 < T) {
            const int ko = (t + 1) * BK;
            ra0 = *(const float4*)(pA0 + ko);
            ra1 = *(const float4*)(pA1 + ko);
            rb0 = wok ? *(const float4*)(pB0 + (size_t)ko * NOUT) : z4;
            rb1 = wok ? *(const float4*)(pB1 + (size_t)ko * NOUT) : z4;
        }

        // ---- compute on current LDS tile ----
#pragma unroll
        for (int kk = 0; kk < BK; ++kk) {
            float4 a = *(const float4*)&As[kk][ty * 4];
            float4 b = *(const float4*)&Bs[kk][tx * 4];
            acc[0][0] += a.x * b.x; acc[0][1] += a.x * b.y; acc[0][2] += a.x * b.z; acc[0][3] += a.x * b.w;
            acc[1][0] += a.y * b.x; acc[1][1] += a.y * b.y; acc[1][2] += a.y * b.z; acc[1][3] += a.y * b.w;
            acc[2][0] += a.z * b.x; acc[2][1] += a.z * b.y; acc[2][2] += a.z * b.z; acc[2][3] += a.z * b.w;
            acc[3][0] += a.w * b.x; acc[3][1] += a.w * b.y; acc[3][2] += a.w * b.z; acc[3][3] += a.w * b.w;
        }
        __syncthreads();   // LDS free for next store
    }

    if (tx * 4 + 3 < NOUT) {
#pragma unroll
        for (int i = 0; i < 4; ++i) {
            int row = r0 + ty * 4 + i;
            if (row < nrows)
                *(float4*)&Hout[(size_t)row * NOUT + tx * 4] =
                    make_float4(acc[i][0], acc[i][1], acc[i][2], acc[i][3]);
        }
    }
}

// Gather aggregation: one wave per node, lane = feature. No atomics.
// out[row] = h[row]*dis[row]^2 + bias + sum_j h[src_j] * nrm_j  (packed pairs)
template<int F>
__global__ __launch_bounds__(256) void k_node_agg(
    const float* __restrict__ h, const float* __restrict__ dis,
    const float* __restrict__ bias, const int* __restrict__ rowptr,
    const unsigned long long* __restrict__ pairP,
    float* __restrict__ out, int n)
{
    const int lane = threadIdx.x & 63;
    int row = (int)((blockIdx.x * blockDim.x + threadIdx.x) >> 6);
    if (row >= n) return;
    row = __builtin_amdgcn_readfirstlane(row);   // wave-uniform -> SGPR addrs

    const int a = rowptr[row], b = rowptr[row + 1];
    float d  = dis[row];
    float dd = d * d;
    float sum = 0.f;
    if (lane < F) sum = h[(size_t)row * F + lane] * dd + bias[lane];

    int j = a;
    for (; j + 4 <= b; j += 4) {
        unsigned long long p0 = pairP[j],     p1 = pairP[j + 1];
        unsigned long long p2 = pairP[j + 2], p3 = pairP[j + 3];
        int   s0 = (int)(unsigned int)p0, s1 = (int)(unsigned int)p1;
        int   s2 = (int)(unsigned int)p2, s3 = (int)(unsigned int)p3;
        float w0 = __uint_as_float((unsigned int)(p0 >> 32));
        float w1 = __uint_as_float((unsigned int)(p1 >> 32));
        float w2 = __uint_as_float((unsigned int)(p2 >> 32));
        float w3 = __uint_as_float((unsigned int)(p3 >> 32));
        if (lane < F) {
            sum += h[(size_t)s0 * F + lane] * w0;
            sum += h[(size_t)s1 * F + lane] * w1;
            sum += h[(size_t)s2 * F + lane] * w2;
            sum += h[(size_t)s3 * F + lane] * w3;
        }
    }
    for (; j < b; ++j) {
        unsigned long long p = pairP[j];
        int s = (int)(unsigned int)p;
        float w = __uint_as_float((unsigned int)(p >> 32));
        if (lane < F) sum += h[(size_t)s * F + lane] * w;
    }
    if (lane < F) out[(size_t)row * F + lane] = sum;
}

// In-place log_softmax over C columns; one wave per row.
template<int C>
__global__ void k_logsoftmax(float* __restrict__ io, int n) {
    const int lane = threadIdx.x & 63;
    int row = (int)((blockIdx.x * blockDim.x + threadIdx.x) >> 6);
    if (row >= n) return;
    float v = (lane < C) ? io[(size_t)row * C + lane] : -INFINITY;
    float m = v;
#pragma unroll
    for (int off = 32; off; off >>= 1) m = fmaxf(m, __shfl_xor(m, off));
    float e = (lane < C) ? expf(v - m) : 0.f;
    float s = e;
#pragma unroll
    for (int off = 32; off; off >>= 1) s += __shfl_xor(s, off);
    float ls = logf(s);
    if (lane < C) io[(size_t)row * C + lane] = v - m - ls;
}

extern "C" void kernel_launch(void* const* d_in, const int* in_sizes, int n_in,
                              void* d_out, int out_size, void* d_ws, size_t ws_size,
                              hipStream_t stream) {
    const float* x  = (const float*)d_in[0];
    const int*   ei = (const int*)  d_in[1];
    const float* ew = (const float*)d_in[2];
    const float* W0 = (const float*)d_in[3];
    const float* b0 = (const float*)d_in[4];
    const float* W1 = (const float*)d_in[5];
    const float* b1 = (const float*)d_in[6];
    const float* W2 = (const float*)d_in[7];
    const float* b2 = (const float*)d_in[8];

    const int E   = in_sizes[2];            // 1600000
    const int H   = in_sizes[4];            // 64
    const int Fin = in_sizes[3] / H;        // 256
    const int N   = in_sizes[0] / Fin;      // 100000
    (void)n_in; (void)out_size; (void)ws_size;

    const int* srcv = ei;                   // edge_index[0]
    const int* dstv = ei + E;               // edge_index[1]

    // ---- workspace layout (64-float = 256B aligned chunks; 8B-safe) ----
    float* ws = (float*)d_ws;
    size_t o = 0;
    auto alloc = [&](size_t cnt) { size_t p = o; o += (cnt + 63) & ~(size_t)63; return p; };
    float* dis   = ws + alloc(N);
    float* bufA  = ws + alloc((size_t)N * 64);       // h
    float* bufB  = ws + alloc((size_t)N * 64);       // agg
    unsigned long long* pairP = (unsigned long long*)(ws + alloc((size_t)E * 2));
    int*   rowptr= (int*)(ws + alloc(N + 1));
    int*   cnt   = (int*)(ws + alloc(N));
    int*   pos   = (int*)(ws + alloc(E));
    int*   bsum  = (int*)(ws + alloc(512));
    int*   boff  = (int*)(ws + alloc(512));
    float* outf  = (float*)d_out;                    // N*40

    const int TB = 256;
    const int nb1 = (N + 255) / 256;                 // scan blocks (391 <= 512)

    // ---- CSR build (counting sort, 1 atomic/edge total) ----
    (void)hipMemsetAsync(cnt, 0, (size_t)N * sizeof(int), stream);
    k_cnt  <<<(E + TB - 1) / TB, TB, 0, stream>>>(dstv, cnt, pos, E);
    k_scan1<<<nb1, 256, 0, stream>>>(cnt, rowptr, bsum, N);
    k_scan2<<<1, 512, 0, stream>>>(bsum, boff, nb1);
    k_scan3<<<(N + TB - 1) / TB, TB, 0, stream>>>(rowptr, boff, N, E);
    k_place<<<(E + TB - 1) / TB, TB, 0, stream>>>(srcv, dstv, ew, rowptr, pos, pairP, E);
    k_deg_dis <<<(N + TB - 1) / TB, TB, 0, stream>>>(pairP, rowptr, dis, N);
    k_norm_csr<<<(N + TB - 1) / TB, TB, 0, stream>>>(pairP, rowptr, dis, N);

    const int gemmGrid = (N + 63) / 64;
    const int aggGrid  = (N * 64 + TB - 1) / TB;     // one wave per node

    // ---- layer 0: x(256) -> 64 ----
    k_gemm<256, 64, false><<<gemmGrid, TB, 0, stream>>>(x, W0, bufA, N);
    k_node_agg<64><<<aggGrid, TB, 0, stream>>>(bufA, dis, b0, rowptr, pairP, bufB, N);

    // ---- layer 1: 64 -> 64 (relu on load) ----
    k_gemm<64, 64, true><<<gemmGrid, TB, 0, stream>>>(bufB, W1, bufA, N);
    k_node_agg<64><<<aggGrid, TB, 0, stream>>>(bufA, dis, b1, rowptr, pairP, bufB, N);

    // ---- layer 2: 64 -> 40, aggregate straight into d_out ----
    k_gemm<64, 40, true><<<gemmGrid, TB, 0, stream>>>(bufB, W2, bufA, N);
    k_node_agg<40><<<aggGrid, TB, 0, stream>>>(bufA, dis, b2, rowptr, pairP, outf, N);

    // ---- log_softmax in-place on d_out ----
    k_logsoftmax<40><<<(N * 64 + TB - 1) / TB, TB, 0, stream>>>(outf, N);
}

// Round 12
// 379.541 us; speedup vs baseline: 11.1408x; 1.1092x over previous
//
#include <hip/hip_runtime.h>
#include <math.h>

// ---------------------------------------------------------------------------
// GCN 3-layer forward for MI355X.
// R5: tiled GEMM. R7: CSR gather agg. R8: counting-sort CSR build (439us).
// R9 FAILED: unrolled T-loop -> VGPR spill. R11: reg-prefetch GEMM (421us).
// R11 profile: k_cnt@70us top (atomic RMW floor, VALU 0.5%); gemm L0 <70us.
// R12: OVERLAP independent work via fused mega-kernels (branch on blockIdx):
//   fused A = gemm-L0 tiles [0,ntA) || k_cnt ; fused B = gemm-L0 tiles
//   [ntA,ntiles) || k_place. Atomic-latency blocks + compute blocks use
//   disjoint pipes -> gemm L0 rides free. Also: log_softmax folded into the
//   last node_agg (row already in wave registers).
// ---------------------------------------------------------------------------

// ---- exclusive scan over cnt[N] -> rowptr, 3 kernels ----
__global__ void k_scan1(const int* __restrict__ cnt, int* __restrict__ excl,
                        int* __restrict__ bsum, int n) {
    __shared__ int sm[256];
    int tid = threadIdx.x;
    int i = blockIdx.x * 256 + tid;
    int v = (i < n) ? cnt[i] : 0;
    sm[tid] = v;
    __syncthreads();
    for (int off = 1; off < 256; off <<= 1) {
        int t = (tid >= off) ? sm[tid - off] : 0;
        __syncthreads();
        sm[tid] += t;
        __syncthreads();
    }
    if (i < n) excl[i] = sm[tid] - v;
    if (tid == 255) bsum[blockIdx.x] = sm[255];
}

__global__ void k_scan2(const int* __restrict__ bsum, int* __restrict__ boff, int nb) {
    __shared__ int sm[512];
    int tid = threadIdx.x;
    int v = (tid < nb) ? bsum[tid] : 0;
    sm[tid] = v;
    __syncthreads();
    for (int off = 1; off < 512; off <<= 1) {
        int t = (tid >= off) ? sm[tid - off] : 0;
        __syncthreads();
        sm[tid] += t;
        __syncthreads();
    }
    boff[tid] = sm[tid] - v;   // exclusive
}

__global__ void k_scan3(int* __restrict__ rowptr, const int* __restrict__ boff,
                        int n, int E) {
    int i = blockIdx.x * blockDim.x + threadIdx.x;
    if (i < n) rowptr[i] += boff[i >> 8];
    if (i == 0) rowptr[n] = E;
}

// Per-node: dis = rsqrt(1 + sum ew) from CSR pairs (payload = ew here).
__global__ void k_deg_dis(const unsigned long long* __restrict__ pairP,
                          const int* __restrict__ rowptr, float* __restrict__ dis, int n) {
    int i = blockIdx.x * blockDim.x + threadIdx.x;
    if (i >= n) return;
    int a = rowptr[i], b = rowptr[i + 1];
    float s = 1.0f;   // self-loop weight
    for (int p = a; p < b; ++p)
        s += __uint_as_float((unsigned int)(pairP[p] >> 32));
    dis[i] = (s > 0.f) ? rsqrtf(s) : 0.f;
}

// Per-node: rewrite pair payload ew -> nrm = dis[s]*ew*dis[d] (in place).
__global__ void k_norm_csr(unsigned long long* __restrict__ pairP,
                           const int* __restrict__ rowptr,
                           const float* __restrict__ dis, int n) {
    int i = blockIdx.x * blockDim.x + threadIdx.x;
    if (i >= n) return;
    int a = rowptr[i], b = rowptr[i + 1];
    float dd = dis[i];
    for (int p = a; p < b; ++p) {
        unsigned long long pk = pairP[p];
        int s = (int)(unsigned int)pk;
        float w = __uint_as_float((unsigned int)(pk >> 32));
        float nrm = dis[s] * w * dd;
        pairP[p] = ((unsigned long long)__float_as_uint(nrm) << 32) | (unsigned int)s;
    }
}

// Tiled GEMM body: Hout = act(X)@W, BM64xBN64xBK32, 4x4 reg tile, reg-prefetch
// of tile t+1, T-loop NOT unrolled (R9 lesson: unrolling -> VGPR explosion).
template<int K, int NOUT, bool RELU_IN>
__device__ __forceinline__ void gemm_tile_body(
    const float* __restrict__ X, const float* __restrict__ W,
    float* __restrict__ Hout, int nrows, int tile)
{
    constexpr int BM = 64, BN = 64, BK = 32;
    constexpr int T  = K / BK;
    __shared__ float As[BK][BM + 4];   // As[k][m]
    __shared__ float Bs[BK][BN + 4];

    const int tid = (int)threadIdx.x;
    const int tx  = tid & 15;          // cols tx*4..+3
    const int ty  = tid >> 4;          // rows ty*4..+3
    const int r0  = tile * BM;

    const int ar = tid >> 3;           // 0..31, rows ar and ar+32
    const int aq = tid & 7;            // float4 index in k-dir
    const int bk = tid >> 4;           // 0..15, k-rows bk and bk+16
    const int bc = tid & 15;           // float4 index in n-dir

    const int rowA0 = min(r0 + ar,      nrows - 1);
    const int rowA1 = min(r0 + ar + 32, nrows - 1);
    const float* pA0 = X + (size_t)rowA0 * K + aq * 4;
    const float* pA1 = X + (size_t)rowA1 * K + aq * 4;
    const bool wok = (bc * 4 + 3 < NOUT);   // W guard (NOUT=40 case)
    const float* pB0 = W + (size_t)bk * NOUT + bc * 4;
    const float* pB1 = W + (size_t)(bk + 16) * NOUT + bc * 4;
    const float4 z4 = make_float4(0.f, 0.f, 0.f, 0.f);

    float4 ra0, ra1, rb0, rb1;
    ra0 = *(const float4*)pA0;
    ra1 = *(const float4*)pA1;
    rb0 = wok ? *(const float4*)pB0 : z4;
    rb1 = wok ? *(const float4*)pB1 : z4;

    float acc[4][4] = {};

#pragma unroll 1
    for (int t = 0; t < T; ++t) {
        if (RELU_IN) {
            ra0.x = fmaxf(ra0.x, 0.f); ra0.y = fmaxf(ra0.y, 0.f);
            ra0.z = fmaxf(ra0.z, 0.f); ra0.w = fmaxf(ra0.w, 0.f);
            ra1.x = fmaxf(ra1.x, 0.f); ra1.y = fmaxf(ra1.y, 0.f);
            ra1.z = fmaxf(ra1.z, 0.f); ra1.w = fmaxf(ra1.w, 0.f);
        }
        As[aq * 4 + 0][ar]      = ra0.x;
        As[aq * 4 + 1][ar]      = ra0.y;
        As[aq * 4 + 2][ar]      = ra0.z;
        As[aq * 4 + 3][ar]      = ra0.w;
        As[aq * 4 + 0][ar + 32] = ra1.x;
        As[aq * 4 + 1][ar + 32] = ra1.y;
        As[aq * 4 + 2][ar + 32] = ra1.z;
        As[aq * 4 + 3][ar + 32] = ra1.w;
        *(float4*)&Bs[bk][bc * 4]      = rb0;
        *(float4*)&Bs[bk + 16][bc * 4] = rb1;
        __syncthreads();

        if (t + 1 < T) {
            const int ko = (t + 1) * BK;
            ra0 = *(const float4*)(pA0 + ko);
            ra1 = *(const float4*)(pA1 + ko);
            rb0 = wok ? *(const float4*)(pB0 + (size_t)ko * NOUT) : z4;
            rb1 = wok ? *(const float4*)(pB1 + (size_t)ko * NOUT) : z4;
        }

#pragma unroll
        for (int kk = 0; kk < BK; ++kk) {
            float4 a = *(const float4*)&As[kk][ty * 4];
            float4 b = *(const float4*)&Bs[kk][tx * 4];
            acc[0][0] += a.x * b.x; acc[0][1] += a.x * b.y; acc[0][2] += a.x * b.z; acc[0][3] += a.x * b.w;
            acc[1][0] += a.y * b.x; acc[1][1] += a.y * b.y; acc[1][2] += a.y * b.z; acc[1][3] += a.y * b.w;
            acc[2][0] += a.z * b.x; acc[2][1] += a.z * b.y; acc[2][2] += a.z * b.z; acc[2][3] += a.z * b.w;
            acc[3][0] += a.w * b.x; acc[3][1] += a.w * b.y; acc[3][2] += a.w * b.z; acc[3][3] += a.w * b.w;
        }
        __syncthreads();
    }

    if (tx * 4 + 3 < NOUT) {
#pragma unroll
        for (int i = 0; i < 4; ++i) {
            int row = r0 + ty * 4 + i;
            if (row < nrows)
                *(float4*)&Hout[(size_t)row * NOUT + tx * 4] =
                    make_float4(acc[i][0], acc[i][1], acc[i][2], acc[i][3]);
        }
    }
}

// Plain GEMM kernel (layers 1 & 2).
template<int K, int NOUT, bool RELU_IN>
__global__ __launch_bounds__(256) void k_gemm(
    const float* __restrict__ X, const float* __restrict__ W,
    float* __restrict__ Hout, int nrows)
{
    gemm_tile_body<K, NOUT, RELU_IN>(X, W, Hout, nrows, (int)blockIdx.x);
}

// Fused A: gemm-L0 tiles [0,ntiles) || k_cnt grid-stride (pos = slot).
template<int K, int NOUT, bool RELU_IN>
__global__ __launch_bounds__(256) void k_gemm_cnt(
    const float* __restrict__ X, const float* __restrict__ W,
    float* __restrict__ Hout, int nrows, int ntiles,
    const int* __restrict__ dst, int* __restrict__ cnt, int* __restrict__ pos, int E)
{
    if ((int)blockIdx.x < ntiles) {
        gemm_tile_body<K, NOUT, RELU_IN>(X, W, Hout, nrows, (int)blockIdx.x);
    } else {
        int bid    = (int)blockIdx.x - ntiles;
        int idx    = bid * 256 + (int)threadIdx.x;
        int stride = ((int)gridDim.x - ntiles) * 256;
        for (int e = idx; e < E; e += stride)
            pos[e] = atomicAdd(&cnt[dst[e]], 1);
    }
}

// Fused B: gemm-L0 tiles [tile0, tile0+ntiles) || k_place (no atomic).
template<int K, int NOUT, bool RELU_IN>
__global__ __launch_bounds__(256) void k_gemm_place(
    const float* __restrict__ X, const float* __restrict__ W,
    float* __restrict__ Hout, int nrows, int tile0, int ntiles,
    const int* __restrict__ src, const int* __restrict__ dst,
    const float* __restrict__ ew, const int* __restrict__ rowptr,
    const int* __restrict__ pos, unsigned long long* __restrict__ pairP, int E)
{
    if ((int)blockIdx.x < ntiles) {
        gemm_tile_body<K, NOUT, RELU_IN>(X, W, Hout, nrows, tile0 + (int)blockIdx.x);
    } else {
        int bid    = (int)blockIdx.x - ntiles;
        int idx    = bid * 256 + (int)threadIdx.x;
        int stride = ((int)gridDim.x - ntiles) * 256;
        for (int e = idx; e < E; e += stride) {
            int d = dst[e];
            int p = rowptr[d] + pos[e];
            unsigned long long pk = (unsigned long long)__float_as_uint(ew[e]) << 32
                                  | (unsigned int)src[e];
            pairP[p] = pk;
        }
    }
}

// Gather aggregation: one wave per node, lane = feature. No atomics.
// out[row] = h[row]*dis^2 + bias + sum_j h[src_j]*nrm_j ; optional fused
// log_softmax epilogue (row lives in wave registers).
template<int F, bool LSM>
__global__ __launch_bounds__(256) void k_node_agg(
    const float* __restrict__ h, const float* __restrict__ dis,
    const float* __restrict__ bias, const int* __restrict__ rowptr,
    const unsigned long long* __restrict__ pairP,
    float* __restrict__ out, int n)
{
    const int lane = threadIdx.x & 63;
    int row = (int)((blockIdx.x * blockDim.x + threadIdx.x) >> 6);
    if (row >= n) return;
    row = __builtin_amdgcn_readfirstlane(row);   // wave-uniform -> SGPR addrs

    const int a = rowptr[row], b = rowptr[row + 1];
    float d  = dis[row];
    float dd = d * d;
    float sum = 0.f;
    if (lane < F) sum = h[(size_t)row * F + lane] * dd + bias[lane];

    int j = a;
    for (; j + 4 <= b; j += 4) {
        unsigned long long p0 = pairP[j],     p1 = pairP[j + 1];
        unsigned long long p2 = pairP[j + 2], p3 = pairP[j + 3];
        int   s0 = (int)(unsigned int)p0, s1 = (int)(unsigned int)p1;
        int   s2 = (int)(unsigned int)p2, s3 = (int)(unsigned int)p3;
        float w0 = __uint_as_float((unsigned int)(p0 >> 32));
        float w1 = __uint_as_float((unsigned int)(p1 >> 32));
        float w2 = __uint_as_float((unsigned int)(p2 >> 32));
        float w3 = __uint_as_float((unsigned int)(p3 >> 32));
        if (lane < F) {
            sum += h[(size_t)s0 * F + lane] * w0;
            sum += h[(size_t)s1 * F + lane] * w1;
            sum += h[(size_t)s2 * F + lane] * w2;
            sum += h[(size_t)s3 * F + lane] * w3;
        }
    }
    for (; j < b; ++j) {
        unsigned long long p = pairP[j];
        int s = (int)(unsigned int)p;
        float w = __uint_as_float((unsigned int)(p >> 32));
        if (lane < F) sum += h[(size_t)s * F + lane] * w;
    }

    if (LSM) {
        float v = (lane < F) ? sum : -INFINITY;
        float m = v;
#pragma unroll
        for (int off = 32; off; off >>= 1) m = fmaxf(m, __shfl_xor(m, off));
        float e = (lane < F) ? expf(v - m) : 0.f;
        float s2 = e;
#pragma unroll
        for (int off = 32; off; off >>= 1) s2 += __shfl_xor(s2, off);
        float ls = logf(s2);
        if (lane < F) out[(size_t)row * F + lane] = v - m - ls;
    } else {
        if (lane < F) out[(size_t)row * F + lane] = sum;
    }
}

extern "C" void kernel_launch(void* const* d_in, const int* in_sizes, int n_in,
                              void* d_out, int out_size, void* d_ws, size_t ws_size,
                              hipStream_t stream) {
    const float* x  = (const float*)d_in[0];
    const int*   ei = (const int*)  d_in[1];
    const float* ew = (const float*)d_in[2];
    const float* W0 = (const float*)d_in[3];
    const float* b0 = (const float*)d_in[4];
    const float* W1 = (const float*)d_in[5];
    const float* b1 = (const float*)d_in[6];
    const float* W2 = (const float*)d_in[7];
    const float* b2 = (const float*)d_in[8];

    const int E   = in_sizes[2];            // 1600000
    const int H   = in_sizes[4];            // 64
    const int Fin = in_sizes[3] / H;        // 256
    const int N   = in_sizes[0] / Fin;      // 100000
    (void)n_in; (void)out_size; (void)ws_size;

    const int* srcv = ei;                   // edge_index[0]
    const int* dstv = ei + E;               // edge_index[1]

    // ---- workspace layout ----
    float* ws = (float*)d_ws;
    size_t o = 0;
    auto alloc = [&](size_t cnt_) { size_t p = o; o += (cnt_ + 63) & ~(size_t)63; return p; };
    float* dis   = ws + alloc(N);
    float* bufA  = ws + alloc((size_t)N * 64);       // h
    float* bufB  = ws + alloc((size_t)N * 64);       // agg
    unsigned long long* pairP = (unsigned long long*)(ws + alloc((size_t)E * 2));
    int*   rowptr= (int*)(ws + alloc(N + 1));
    int*   cnt   = (int*)(ws + alloc(N));
    int*   pos   = (int*)(ws + alloc(E));
    int*   bsum  = (int*)(ws + alloc(512));
    int*   boff  = (int*)(ws + alloc(512));
    float* outf  = (float*)d_out;                    // N*40

    const int TB  = 256;
    const int nb1 = (N + 255) / 256;                 // scan blocks (391 <= 512)

    const int ntiles = (N + 63) / 64;                // 1563 gemm-L0 tiles
    const int ntA = (ntiles + 1) / 2;                // first half fused w/ cnt
    const int ntB = ntiles - ntA;                    // second half fused w/ place
    const int XB  = 2048;                            // extra blocks for cnt/place

    // ---- fused A: gemm L0 (tiles 0..ntA) || counting histogram ----
    (void)hipMemsetAsync(cnt, 0, (size_t)N * sizeof(int), stream);
    k_gemm_cnt<256, 64, false><<<ntA + XB, TB, 0, stream>>>(
        x, W0, bufA, N, ntA, dstv, cnt, pos, E);

    // ---- scan cnt -> rowptr ----
    k_scan1<<<nb1, 256, 0, stream>>>(cnt, rowptr, bsum, N);
    k_scan2<<<1, 512, 0, stream>>>(bsum, boff, nb1);
    k_scan3<<<(N + TB - 1) / TB, TB, 0, stream>>>(rowptr, boff, N, E);

    // ---- fused B: gemm L0 (tiles ntA..ntiles) || place packed pairs ----
    k_gemm_place<256, 64, false><<<ntB + XB, TB, 0, stream>>>(
        x, W0, bufA, N, ntA, ntB, srcv, dstv, ew, rowptr, pos, pairP, E);

    // ---- dis + norm over CSR ----
    k_deg_dis <<<(N + TB - 1) / TB, TB, 0, stream>>>(pairP, rowptr, dis, N);
    k_norm_csr<<<(N + TB - 1) / TB, TB, 0, stream>>>(pairP, rowptr, dis, N);

    const int aggGrid = (N * 64 + TB - 1) / TB;      // one wave per node

    // ---- layer 0 aggregate ----
    k_node_agg<64, false><<<aggGrid, TB, 0, stream>>>(bufA, dis, b0, rowptr, pairP, bufB, N);

    // ---- layer 1: 64 -> 64 (relu on load) ----
    k_gemm<64, 64, true><<<ntiles, TB, 0, stream>>>(bufB, W1, bufA, N);
    k_node_agg<64, false><<<aggGrid, TB, 0, stream>>>(bufA, dis, b1, rowptr, pairP, bufB, N);

    // ---- layer 2: 64 -> 40, aggregate + fused log_softmax into d_out ----
    k_gemm<64, 40, true><<<ntiles, TB, 0, stream>>>(bufB, W2, bufA, N);
    k_node_agg<40, true><<<aggGrid, TB, 0, stream>>>(bufA, dis, b2, rowptr, pairP, outf, N);
}

// Round 13
// 349.354 us; speedup vs baseline: 12.1034x; 1.0864x over previous
//
#include <hip/hip_runtime.h>
#include <math.h>

// ---------------------------------------------------------------------------
// GCN 3-layer forward for MI355X.
// R5: tiled GEMM. R7: CSR gather agg. R8: counting-sort build. R11: reg-
//   prefetch GEMM (421us). R12: overlap fused A/B + fused logsoftmax (380us).
// R13: (a) bf16 h-buffer for the gather path — agg moves E*F*2B instead of
//   *4B (fp32 trunk preserved: agg out / gemm in stay fp32; rounding enters
//   once per layer); (b) ALL 1563 L0-gemm tiles under the k_cnt atomic floor
//   (~70us); k_place standalone.
// ---------------------------------------------------------------------------

__device__ __forceinline__ unsigned short f2bf(float f) {   // RNE fp32->bf16
    unsigned u = __float_as_uint(f);
    u += 0x7FFFu + ((u >> 16) & 1u);
    return (unsigned short)(u >> 16);
}
__device__ __forceinline__ float bf2f(unsigned short h) {
    return __uint_as_float(((unsigned)h) << 16);
}

// ---- exclusive scan over cnt[N] -> rowptr, 3 kernels ----
__global__ void k_scan1(const int* __restrict__ cnt, int* __restrict__ excl,
                        int* __restrict__ bsum, int n) {
    __shared__ int sm[256];
    int tid = threadIdx.x;
    int i = blockIdx.x * 256 + tid;
    int v = (i < n) ? cnt[i] : 0;
    sm[tid] = v;
    __syncthreads();
    for (int off = 1; off < 256; off <<= 1) {
        int t = (tid >= off) ? sm[tid - off] : 0;
        __syncthreads();
        sm[tid] += t;
        __syncthreads();
    }
    if (i < n) excl[i] = sm[tid] - v;
    if (tid == 255) bsum[blockIdx.x] = sm[255];
}

__global__ void k_scan2(const int* __restrict__ bsum, int* __restrict__ boff, int nb) {
    __shared__ int sm[512];
    int tid = threadIdx.x;
    int v = (tid < nb) ? bsum[tid] : 0;
    sm[tid] = v;
    __syncthreads();
    for (int off = 1; off < 512; off <<= 1) {
        int t = (tid >= off) ? sm[tid - off] : 0;
        __syncthreads();
        sm[tid] += t;
        __syncthreads();
    }
    boff[tid] = sm[tid] - v;   // exclusive
}

__global__ void k_scan3(int* __restrict__ rowptr, const int* __restrict__ boff,
                        int n, int E) {
    int i = blockIdx.x * blockDim.x + threadIdx.x;
    if (i < n) rowptr[i] += boff[i >> 8];
    if (i == 0) rowptr[n] = E;
}

// Place edges into dst-grouped slots (NO atomic): 8B packed {src, ew}.
__global__ void k_place(const int* __restrict__ src, const int* __restrict__ dst,
                        const float* __restrict__ ew, const int* __restrict__ rowptr,
                        const int* __restrict__ pos, unsigned long long* __restrict__ pairP,
                        int E) {
    int e = blockIdx.x * blockDim.x + threadIdx.x;
    if (e < E) {
        int d = dst[e];
        int p = rowptr[d] + pos[e];
        unsigned long long pk = (unsigned long long)__float_as_uint(ew[e]) << 32
                              | (unsigned int)src[e];
        pairP[p] = pk;
    }
}

// Per-node: dis = rsqrt(1 + sum ew) from CSR pairs (payload = ew here).
__global__ void k_deg_dis(const unsigned long long* __restrict__ pairP,
                          const int* __restrict__ rowptr, float* __restrict__ dis, int n) {
    int i = blockIdx.x * blockDim.x + threadIdx.x;
    if (i >= n) return;
    int a = rowptr[i], b = rowptr[i + 1];
    float s = 1.0f;   // self-loop weight
    for (int p = a; p < b; ++p)
        s += __uint_as_float((unsigned int)(pairP[p] >> 32));
    dis[i] = (s > 0.f) ? rsqrtf(s) : 0.f;
}

// Per-node: rewrite pair payload ew -> nrm = dis[s]*ew*dis[d] (in place).
__global__ void k_norm_csr(unsigned long long* __restrict__ pairP,
                           const int* __restrict__ rowptr,
                           const float* __restrict__ dis, int n) {
    int i = blockIdx.x * blockDim.x + threadIdx.x;
    if (i >= n) return;
    int a = rowptr[i], b = rowptr[i + 1];
    float dd = dis[i];
    for (int p = a; p < b; ++p) {
        unsigned long long pk = pairP[p];
        int s = (int)(unsigned int)pk;
        float w = __uint_as_float((unsigned int)(pk >> 32));
        float nrm = dis[s] * w * dd;
        pairP[p] = ((unsigned long long)__float_as_uint(nrm) << 32) | (unsigned int)s;
    }
}

// Tiled GEMM body: HB(bf16) = act(X fp32)@W, BM64xBN64xBK32, 4x4 reg tile,
// reg-prefetch of tile t+1, T-loop NOT unrolled (R9 lesson).
template<int K, int NOUT, bool RELU_IN>
__device__ __forceinline__ void gemm_tile_body(
    const float* __restrict__ X, const float* __restrict__ W,
    unsigned short* __restrict__ HB, int nrows, int tile)
{
    constexpr int BM = 64, BN = 64, BK = 32;
    constexpr int T  = K / BK;
    __shared__ float As[BK][BM + 4];   // As[k][m]
    __shared__ float Bs[BK][BN + 4];

    const int tid = (int)threadIdx.x;
    const int tx  = tid & 15;          // cols tx*4..+3
    const int ty  = tid >> 4;          // rows ty*4..+3
    const int r0  = tile * BM;

    const int ar = tid >> 3;           // 0..31, rows ar and ar+32
    const int aq = tid & 7;            // float4 index in k-dir
    const int bk = tid >> 4;           // 0..15, k-rows bk and bk+16
    const int bc = tid & 15;           // float4 index in n-dir

    const int rowA0 = min(r0 + ar,      nrows - 1);
    const int rowA1 = min(r0 + ar + 32, nrows - 1);
    const float* pA0 = X + (size_t)rowA0 * K + aq * 4;
    const float* pA1 = X + (size_t)rowA1 * K + aq * 4;
    const bool wok = (bc * 4 + 3 < NOUT);   // W guard (NOUT=40 case)
    const float* pB0 = W + (size_t)bk * NOUT + bc * 4;
    const float* pB1 = W + (size_t)(bk + 16) * NOUT + bc * 4;
    const float4 z4 = make_float4(0.f, 0.f, 0.f, 0.f);

    float4 ra0, ra1, rb0, rb1;
    ra0 = *(const float4*)pA0;
    ra1 = *(const float4*)pA1;
    rb0 = wok ? *(const float4*)pB0 : z4;
    rb1 = wok ? *(const float4*)pB1 : z4;

    float acc[4][4] = {};

#pragma unroll 1
    for (int t = 0; t < T; ++t) {
        if (RELU_IN) {
            ra0.x = fmaxf(ra0.x, 0.f); ra0.y = fmaxf(ra0.y, 0.f);
            ra0.z = fmaxf(ra0.z, 0.f); ra0.w = fmaxf(ra0.w, 0.f);
            ra1.x = fmaxf(ra1.x, 0.f); ra1.y = fmaxf(ra1.y, 0.f);
            ra1.z = fmaxf(ra1.z, 0.f); ra1.w = fmaxf(ra1.w, 0.f);
        }
        As[aq * 4 + 0][ar]      = ra0.x;
        As[aq * 4 + 1][ar]      = ra0.y;
        As[aq * 4 + 2][ar]      = ra0.z;
        As[aq * 4 + 3][ar]      = ra0.w;
        As[aq * 4 + 0][ar + 32] = ra1.x;
        As[aq * 4 + 1][ar + 32] = ra1.y;
        As[aq * 4 + 2][ar + 32] = ra1.z;
        As[aq * 4 + 3][ar + 32] = ra1.w;
        *(float4*)&Bs[bk][bc * 4]      = rb0;
        *(float4*)&Bs[bk + 16][bc * 4] = rb1;
        __syncthreads();

        if (t + 1 < T) {
            const int ko = (t + 1) * BK;
            ra0 = *(const float4*)(pA0 + ko);
            ra1 = *(const float4*)(pA1 + ko);
            rb0 = wok ? *(const float4*)(pB0 + (size_t)ko * NOUT) : z4;
            rb1 = wok ? *(const float4*)(pB1 + (size_t)ko * NOUT) : z4;
        }

#pragma unroll
        for (int kk = 0; kk < BK; ++kk) {
            float4 a = *(const float4*)&As[kk][ty * 4];
            float4 b = *(const float4*)&Bs[kk][tx * 4];
            acc[0][0] += a.x * b.x; acc[0][1] += a.x * b.y; acc[0][2] += a.x * b.z; acc[0][3] += a.x * b.w;
            acc[1][0] += a.y * b.x; acc[1][1] += a.y * b.y; acc[1][2] += a.y * b.z; acc[1][3] += a.y * b.w;
            acc[2][0] += a.z * b.x; acc[2][1] += a.z * b.y; acc[2][2] += a.z * b.z; acc[2][3] += a.z * b.w;
            acc[3][0] += a.w * b.x; acc[3][1] += a.w * b.y; acc[3][2] += a.w * b.z; acc[3][3] += a.w * b.w;
        }
        __syncthreads();
    }

    if (tx * 4 + 3 < NOUT) {
#pragma unroll
        for (int i = 0; i < 4; ++i) {
            int row = r0 + ty * 4 + i;
            if (row < nrows) {
                ushort4 hv;
                hv.x = f2bf(acc[i][0]); hv.y = f2bf(acc[i][1]);
                hv.z = f2bf(acc[i][2]); hv.w = f2bf(acc[i][3]);
                *(ushort4*)&HB[(size_t)row * NOUT + tx * 4] = hv;
            }
        }
    }
}

// Plain GEMM kernel (layers 1 & 2).
template<int K, int NOUT, bool RELU_IN>
__global__ __launch_bounds__(256) void k_gemm(
    const float* __restrict__ X, const float* __restrict__ W,
    unsigned short* __restrict__ HB, int nrows)
{
    gemm_tile_body<K, NOUT, RELU_IN>(X, W, HB, nrows, (int)blockIdx.x);
}

// Fused: ALL gemm-L0 tiles || k_cnt grid-stride (pos = atomic return slot).
template<int K, int NOUT, bool RELU_IN>
__global__ __launch_bounds__(256) void k_gemm_cnt(
    const float* __restrict__ X, const float* __restrict__ W,
    unsigned short* __restrict__ HB, int nrows, int ntiles,
    const int* __restrict__ dst, int* __restrict__ cnt, int* __restrict__ pos, int E)
{
    if ((int)blockIdx.x < ntiles) {
        gemm_tile_body<K, NOUT, RELU_IN>(X, W, HB, nrows, (int)blockIdx.x);
    } else {
        int bid    = (int)blockIdx.x - ntiles;
        int idx    = bid * 256 + (int)threadIdx.x;
        int stride = ((int)gridDim.x - ntiles) * 256;
        for (int e = idx; e < E; e += stride)
            pos[e] = atomicAdd(&cnt[dst[e]], 1);
    }
}

// Gather aggregation: one wave per node, lane = feature. No atomics.
// out = bf2f(h[row])*dis^2 + bias + sum_j bf2f(h[src_j])*nrm_j ; optional
// fused log_softmax epilogue. Gathers are bf16: 2B/lane, 128B/row-wave.
template<int F, bool LSM>
__global__ __launch_bounds__(256) void k_node_agg(
    const unsigned short* __restrict__ hB, const float* __restrict__ dis,
    const float* __restrict__ bias, const int* __restrict__ rowptr,
    const unsigned long long* __restrict__ pairP,
    float* __restrict__ out, int n)
{
    const int lane = threadIdx.x & 63;
    int row = (int)((blockIdx.x * blockDim.x + threadIdx.x) >> 6);
    if (row >= n) return;
    row = __builtin_amdgcn_readfirstlane(row);   // wave-uniform -> SGPR addrs

    const int a = rowptr[row], b = rowptr[row + 1];
    float d  = dis[row];
    float dd = d * d;
    float sum = 0.f;
    if (lane < F) sum = bf2f(hB[(size_t)row * F + lane]) * dd + bias[lane];

    int j = a;
    for (; j + 4 <= b; j += 4) {
        unsigned long long p0 = pairP[j],     p1 = pairP[j + 1];
        unsigned long long p2 = pairP[j + 2], p3 = pairP[j + 3];
        int   s0 = (int)(unsigned int)p0, s1 = (int)(unsigned int)p1;
        int   s2 = (int)(unsigned int)p2, s3 = (int)(unsigned int)p3;
        float w0 = __uint_as_float((unsigned int)(p0 >> 32));
        float w1 = __uint_as_float((unsigned int)(p1 >> 32));
        float w2 = __uint_as_float((unsigned int)(p2 >> 32));
        float w3 = __uint_as_float((unsigned int)(p3 >> 32));
        if (lane < F) {
            sum += bf2f(hB[(size_t)s0 * F + lane]) * w0;
            sum += bf2f(hB[(size_t)s1 * F + lane]) * w1;
            sum += bf2f(hB[(size_t)s2 * F + lane]) * w2;
            sum += bf2f(hB[(size_t)s3 * F + lane]) * w3;
        }
    }
    for (; j < b; ++j) {
        unsigned long long p = pairP[j];
        int s = (int)(unsigned int)p;
        float w = __uint_as_float((unsigned int)(p >> 32));
        if (lane < F) sum += bf2f(hB[(size_t)s * F + lane]) * w;
    }

    if (LSM) {
        float v = (lane < F) ? sum : -INFINITY;
        float m = v;
#pragma unroll
        for (int off = 32; off; off >>= 1) m = fmaxf(m, __shfl_xor(m, off));
        float e = (lane < F) ? expf(v - m) : 0.f;
        float s2 = e;
#pragma unroll
        for (int off = 32; off; off >>= 1) s2 += __shfl_xor(s2, off);
        float ls = logf(s2);
        if (lane < F) out[(size_t)row * F + lane] = v - m - ls;
    } else {
        if (lane < F) out[(size_t)row * F + lane] = sum;
    }
}

extern "C" void kernel_launch(void* const* d_in, const int* in_sizes, int n_in,
                              void* d_out, int out_size, void* d_ws, size_t ws_size,
                              hipStream_t stream) {
    const float* x  = (const float*)d_in[0];
    const int*   ei = (const int*)  d_in[1];
    const float* ew = (const float*)d_in[2];
    const float* W0 = (const float*)d_in[3];
    const float* b0 = (const float*)d_in[4];
    const float* W1 = (const float*)d_in[5];
    const float* b1 = (const float*)d_in[6];
    const float* W2 = (const float*)d_in[7];
    const float* b2 = (const float*)d_in[8];

    const int E   = in_sizes[2];            // 1600000
    const int H   = in_sizes[4];            // 64
    const int Fin = in_sizes[3] / H;        // 256
    const int N   = in_sizes[0] / Fin;      // 100000
    (void)n_in; (void)out_size; (void)ws_size;

    const int* srcv = ei;                   // edge_index[0]
    const int* dstv = ei + E;               // edge_index[1]

    // ---- workspace layout ----
    float* ws = (float*)d_ws;
    size_t o = 0;
    auto alloc = [&](size_t cnt_) { size_t p = o; o += (cnt_ + 63) & ~(size_t)63; return p; };
    float* dis   = ws + alloc(N);
    float* bufB  = ws + alloc((size_t)N * 64);               // agg out (fp32 trunk)
    unsigned short* hB = (unsigned short*)(ws + alloc((size_t)N * 32));  // bf16 h
    unsigned long long* pairP = (unsigned long long*)(ws + alloc((size_t)E * 2));
    int*   rowptr= (int*)(ws + alloc(N + 1));
    int*   cnt   = (int*)(ws + alloc(N));
    int*   pos   = (int*)(ws + alloc(E));
    int*   bsum  = (int*)(ws + alloc(512));
    int*   boff  = (int*)(ws + alloc(512));
    float* outf  = (float*)d_out;                            // N*40

    const int TB  = 256;
    const int nb1 = (N + 255) / 256;                 // scan blocks (391 <= 512)
    const int ntiles = (N + 63) / 64;                // 1563 gemm tiles
    const int XB  = 2048;                            // cnt blocks

    // ---- fused: FULL gemm L0 || counting histogram (cnt-bound ~70us) ----
    (void)hipMemsetAsync(cnt, 0, (size_t)N * sizeof(int), stream);
    k_gemm_cnt<256, 64, false><<<ntiles + XB, TB, 0, stream>>>(
        x, W0, hB, N, ntiles, dstv, cnt, pos, E);

    // ---- scan cnt -> rowptr ----
    k_scan1<<<nb1, 256, 0, stream>>>(cnt, rowptr, bsum, N);
    k_scan2<<<1, 512, 0, stream>>>(bsum, boff, nb1);
    k_scan3<<<(N + TB - 1) / TB, TB, 0, stream>>>(rowptr, boff, N, E);

    // ---- place packed pairs (no atomic) ----
    k_place<<<(E + TB - 1) / TB, TB, 0, stream>>>(srcv, dstv, ew, rowptr, pos, pairP, E);

    // ---- dis + norm over CSR ----
    k_deg_dis <<<(N + TB - 1) / TB, TB, 0, stream>>>(pairP, rowptr, dis, N);
    k_norm_csr<<<(N + TB - 1) / TB, TB, 0, stream>>>(pairP, rowptr, dis, N);

    const int aggGrid = (N * 64 + TB - 1) / TB;      // one wave per node

    // ---- layer 0 aggregate (bf16 gather) ----
    k_node_agg<64, false><<<aggGrid, TB, 0, stream>>>(hB, dis, b0, rowptr, pairP, bufB, N);

    // ---- layer 1: 64 -> 64 (relu on load) ----
    k_gemm<64, 64, true><<<ntiles, TB, 0, stream>>>(bufB, W1, hB, N);
    k_node_agg<64, false><<<aggGrid, TB, 0, stream>>>(hB, dis, b1, rowptr, pairP, bufB, N);

    // ---- layer 2: 64 -> 40, aggregate + fused log_softmax into d_out ----
    k_gemm<64, 40, true><<<ntiles, TB, 0, stream>>>(bufB, W2, hB, N);
    k_node_agg<40, true><<<aggGrid, TB, 0, stream>>>(hB, dis, b2, rowptr, pairP, outf, N);
}

// Round 14
// 342.533 us; speedup vs baseline: 12.3445x; 1.0199x over previous
//
#include <hip/hip_runtime.h>
#include <math.h>

// ---------------------------------------------------------------------------
// GCN 3-layer forward for MI355X.
// R5: tiled GEMM. R7: CSR gather agg. R8: counting-sort build. R11: reg-
//   prefetch GEMM (421us). R12: overlap fused A/B (380). R13: bf16 gather
//   buffer + full-L0 fusion (349) — but fused kernel 75->95us: GEMM tiles
//   at LOW blockIdx filled the residency window first, cnt started late.
// R14: INTERLEAVE roles by blockIdx (even=cnt, odd=gemm in paired region,
//   tail=remaining gemm tiles) + trim cnt blocks 2048->1024. Every residency
//   window now contains both types -> cnt starts at t=0, gemm rides under
//   its ~70us atomic floor.
// ---------------------------------------------------------------------------

__device__ __forceinline__ unsigned short f2bf(float f) {   // RNE fp32->bf16
    unsigned u = __float_as_uint(f);
    u += 0x7FFFu + ((u >> 16) & 1u);
    return (unsigned short)(u >> 16);
}
__device__ __forceinline__ float bf2f(unsigned short h) {
    return __uint_as_float(((unsigned)h) << 16);
}

// ---- exclusive scan over cnt[N] -> rowptr, 3 kernels ----
__global__ void k_scan1(const int* __restrict__ cnt, int* __restrict__ excl,
                        int* __restrict__ bsum, int n) {
    __shared__ int sm[256];
    int tid = threadIdx.x;
    int i = blockIdx.x * 256 + tid;
    int v = (i < n) ? cnt[i] : 0;
    sm[tid] = v;
    __syncthreads();
    for (int off = 1; off < 256; off <<= 1) {
        int t = (tid >= off) ? sm[tid - off] : 0;
        __syncthreads();
        sm[tid] += t;
        __syncthreads();
    }
    if (i < n) excl[i] = sm[tid] - v;
    if (tid == 255) bsum[blockIdx.x] = sm[255];
}

__global__ void k_scan2(const int* __restrict__ bsum, int* __restrict__ boff, int nb) {
    __shared__ int sm[512];
    int tid = threadIdx.x;
    int v = (tid < nb) ? bsum[tid] : 0;
    sm[tid] = v;
    __syncthreads();
    for (int off = 1; off < 512; off <<= 1) {
        int t = (tid >= off) ? sm[tid - off] : 0;
        __syncthreads();
        sm[tid] += t;
        __syncthreads();
    }
    boff[tid] = sm[tid] - v;   // exclusive
}

__global__ void k_scan3(int* __restrict__ rowptr, const int* __restrict__ boff,
                        int n, int E) {
    int i = blockIdx.x * blockDim.x + threadIdx.x;
    if (i < n) rowptr[i] += boff[i >> 8];
    if (i == 0) rowptr[n] = E;
}

// Place edges into dst-grouped slots (NO atomic): 8B packed {src, ew}.
__global__ void k_place(const int* __restrict__ src, const int* __restrict__ dst,
                        const float* __restrict__ ew, const int* __restrict__ rowptr,
                        const int* __restrict__ pos, unsigned long long* __restrict__ pairP,
                        int E) {
    int e = blockIdx.x * blockDim.x + threadIdx.x;
    if (e < E) {
        int d = dst[e];
        int p = rowptr[d] + pos[e];
        unsigned long long pk = (unsigned long long)__float_as_uint(ew[e]) << 32
                              | (unsigned int)src[e];
        pairP[p] = pk;
    }
}

// Per-node: dis = rsqrt(1 + sum ew) from CSR pairs (payload = ew here).
__global__ void k_deg_dis(const unsigned long long* __restrict__ pairP,
                          const int* __restrict__ rowptr, float* __restrict__ dis, int n) {
    int i = blockIdx.x * blockDim.x + threadIdx.x;
    if (i >= n) return;
    int a = rowptr[i], b = rowptr[i + 1];
    float s = 1.0f;   // self-loop weight
    for (int p = a; p < b; ++p)
        s += __uint_as_float((unsigned int)(pairP[p] >> 32));
    dis[i] = (s > 0.f) ? rsqrtf(s) : 0.f;
}

// Per-node: rewrite pair payload ew -> nrm = dis[s]*ew*dis[d] (in place).
__global__ void k_norm_csr(unsigned long long* __restrict__ pairP,
                           const int* __restrict__ rowptr,
                           const float* __restrict__ dis, int n) {
    int i = blockIdx.x * blockDim.x + threadIdx.x;
    if (i >= n) return;
    int a = rowptr[i], b = rowptr[i + 1];
    float dd = dis[i];
    for (int p = a; p < b; ++p) {
        unsigned long long pk = pairP[p];
        int s = (int)(unsigned int)pk;
        float w = __uint_as_float((unsigned int)(pk >> 32));
        float nrm = dis[s] * w * dd;
        pairP[p] = ((unsigned long long)__float_as_uint(nrm) << 32) | (unsigned int)s;
    }
}

// Tiled GEMM body: HB(bf16) = act(X fp32)@W, BM64xBN64xBK32, 4x4 reg tile,
// reg-prefetch of tile t+1, T-loop NOT unrolled (R9 lesson).
template<int K, int NOUT, bool RELU_IN>
__device__ __forceinline__ void gemm_tile_body(
    const float* __restrict__ X, const float* __restrict__ W,
    unsigned short* __restrict__ HB, int nrows, int tile)
{
    constexpr int BM = 64, BN = 64, BK = 32;
    constexpr int T  = K / BK;
    __shared__ float As[BK][BM + 4];   // As[k][m]
    __shared__ float Bs[BK][BN + 4];

    const int tid = (int)threadIdx.x;
    const int tx  = tid & 15;          // cols tx*4..+3
    const int ty  = tid >> 4;          // rows ty*4..+3
    const int r0  = tile * BM;

    const int ar = tid >> 3;           // 0..31, rows ar and ar+32
    const int aq = tid & 7;            // float4 index in k-dir
    const int bk = tid >> 4;           // 0..15, k-rows bk and bk+16
    const int bc = tid & 15;           // float4 index in n-dir

    const int rowA0 = min(r0 + ar,      nrows - 1);
    const int rowA1 = min(r0 + ar + 32, nrows - 1);
    const float* pA0 = X + (size_t)rowA0 * K + aq * 4;
    const float* pA1 = X + (size_t)rowA1 * K + aq * 4;
    const bool wok = (bc * 4 + 3 < NOUT);   // W guard (NOUT=40 case)
    const float* pB0 = W + (size_t)bk * NOUT + bc * 4;
    const float* pB1 = W + (size_t)(bk + 16) * NOUT + bc * 4;
    const float4 z4 = make_float4(0.f, 0.f, 0.f, 0.f);

    float4 ra0, ra1, rb0, rb1;
    ra0 = *(const float4*)pA0;
    ra1 = *(const float4*)pA1;
    rb0 = wok ? *(const float4*)pB0 : z4;
    rb1 = wok ? *(const float4*)pB1 : z4;

    float acc[4][4] = {};

#pragma unroll 1
    for (int t = 0; t < T; ++t) {
        if (RELU_IN) {
            ra0.x = fmaxf(ra0.x, 0.f); ra0.y = fmaxf(ra0.y, 0.f);
            ra0.z = fmaxf(ra0.z, 0.f); ra0.w = fmaxf(ra0.w, 0.f);
            ra1.x = fmaxf(ra1.x, 0.f); ra1.y = fmaxf(ra1.y, 0.f);
            ra1.z = fmaxf(ra1.z, 0.f); ra1.w = fmaxf(ra1.w, 0.f);
        }
        As[aq * 4 + 0][ar]      = ra0.x;
        As[aq * 4 + 1][ar]      = ra0.y;
        As[aq * 4 + 2][ar]      = ra0.z;
        As[aq * 4 + 3][ar]      = ra0.w;
        As[aq * 4 + 0][ar + 32] = ra1.x;
        As[aq * 4 + 1][ar + 32] = ra1.y;
        As[aq * 4 + 2][ar + 32] = ra1.z;
        As[aq * 4 + 3][ar + 32] = ra1.w;
        *(float4*)&Bs[bk][bc * 4]      = rb0;
        *(float4*)&Bs[bk + 16][bc * 4] = rb1;
        __syncthreads();

        if (t + 1 < T) {
            const int ko = (t + 1) * BK;
            ra0 = *(const float4*)(pA0 + ko);
            ra1 = *(const float4*)(pA1 + ko);
            rb0 = wok ? *(const float4*)(pB0 + (size_t)ko * NOUT) : z4;
            rb1 = wok ? *(const float4*)(pB1 + (size_t)ko * NOUT) : z4;
        }

#pragma unroll
        for (int kk = 0; kk < BK; ++kk) {
            float4 a = *(const float4*)&As[kk][ty * 4];
            float4 b = *(const float4*)&Bs[kk][tx * 4];
            acc[0][0] += a.x * b.x; acc[0][1] += a.x * b.y; acc[0][2] += a.x * b.z; acc[0][3] += a.x * b.w;
            acc[1][0] += a.y * b.x; acc[1][1] += a.y * b.y; acc[1][2] += a.y * b.z; acc[1][3] += a.y * b.w;
            acc[2][0] += a.z * b.x; acc[2][1] += a.z * b.y; acc[2][2] += a.z * b.z; acc[2][3] += a.z * b.w;
            acc[3][0] += a.w * b.x; acc[3][1] += a.w * b.y; acc[3][2] += a.w * b.z; acc[3][3] += a.w * b.w;
        }
        __syncthreads();
    }

    if (tx * 4 + 3 < NOUT) {
#pragma unroll
        for (int i = 0; i < 4; ++i) {
            int row = r0 + ty * 4 + i;
            if (row < nrows) {
                ushort4 hv;
                hv.x = f2bf(acc[i][0]); hv.y = f2bf(acc[i][1]);
                hv.z = f2bf(acc[i][2]); hv.w = f2bf(acc[i][3]);
                *(ushort4*)&HB[(size_t)row * NOUT + tx * 4] = hv;
            }
        }
    }
}

// Plain GEMM kernel (layers 1 & 2).
template<int K, int NOUT, bool RELU_IN>
__global__ __launch_bounds__(256) void k_gemm(
    const float* __restrict__ X, const float* __restrict__ W,
    unsigned short* __restrict__ HB, int nrows)
{
    gemm_tile_body<K, NOUT, RELU_IN>(X, W, HB, nrows, (int)blockIdx.x);
}

// Fused, INTERLEAVED: paired region [0, 2*min(ntiles,ncnt)): even=cnt,
// odd=gemm; tail = leftover blocks of the larger role. Every residency
// window holds both types -> cnt's atomic floor hides the gemm.
template<int K, int NOUT, bool RELU_IN>
__global__ __launch_bounds__(256) void k_gemm_cnt(
    const float* __restrict__ X, const float* __restrict__ W,
    unsigned short* __restrict__ HB, int nrows, int ntiles, int ncnt,
    const int* __restrict__ dst, int* __restrict__ cnt, int* __restrict__ pos, int E)
{
    const int b  = (int)blockIdx.x;
    const int m  = min(ntiles, ncnt);
    bool isCnt; int idx;
    if (b < 2 * m) {
        isCnt = ((b & 1) == 0);
        idx   = b >> 1;
    } else {
        int rem = b - 2 * m;
        isCnt = (ncnt > ntiles);
        idx   = m + rem;
    }
    if (!isCnt) {
        gemm_tile_body<K, NOUT, RELU_IN>(X, W, HB, nrows, idx);
    } else {
        int e0     = idx * 256 + (int)threadIdx.x;
        int stride = ncnt * 256;
        for (int e = e0; e < E; e += stride)
            pos[e] = atomicAdd(&cnt[dst[e]], 1);
    }
}

// Gather aggregation: one wave per node, lane = feature. No atomics.
// out = bf2f(h[row])*dis^2 + bias + sum_j bf2f(h[src_j])*nrm_j ; optional
// fused log_softmax epilogue. Gathers are bf16: 2B/lane, 128B/row-wave.
template<int F, bool LSM>
__global__ __launch_bounds__(256) void k_node_agg(
    const unsigned short* __restrict__ hB, const float* __restrict__ dis,
    const float* __restrict__ bias, const int* __restrict__ rowptr,
    const unsigned long long* __restrict__ pairP,
    float* __restrict__ out, int n)
{
    const int lane = threadIdx.x & 63;
    int row = (int)((blockIdx.x * blockDim.x + threadIdx.x) >> 6);
    if (row >= n) return;
    row = __builtin_amdgcn_readfirstlane(row);   // wave-uniform -> SGPR addrs

    const int a = rowptr[row], b = rowptr[row + 1];
    float d  = dis[row];
    float dd = d * d;
    float sum = 0.f;
    if (lane < F) sum = bf2f(hB[(size_t)row * F + lane]) * dd + bias[lane];

    int j = a;
    for (; j + 4 <= b; j += 4) {
        unsigned long long p0 = pairP[j],     p1 = pairP[j + 1];
        unsigned long long p2 = pairP[j + 2], p3 = pairP[j + 3];
        int   s0 = (int)(unsigned int)p0, s1 = (int)(unsigned int)p1;
        int   s2 = (int)(unsigned int)p2, s3 = (int)(unsigned int)p3;
        float w0 = __uint_as_float((unsigned int)(p0 >> 32));
        float w1 = __uint_as_float((unsigned int)(p1 >> 32));
        float w2 = __uint_as_float((unsigned int)(p2 >> 32));
        float w3 = __uint_as_float((unsigned int)(p3 >> 32));
        if (lane < F) {
            sum += bf2f(hB[(size_t)s0 * F + lane]) * w0;
            sum += bf2f(hB[(size_t)s1 * F + lane]) * w1;
            sum += bf2f(hB[(size_t)s2 * F + lane]) * w2;
            sum += bf2f(hB[(size_t)s3 * F + lane]) * w3;
        }
    }
    for (; j < b; ++j) {
        unsigned long long p = pairP[j];
        int s = (int)(unsigned int)p;
        float w = __uint_as_float((unsigned int)(p >> 32));
        if (lane < F) sum += bf2f(hB[(size_t)s * F + lane]) * w;
    }

    if (LSM) {
        float v = (lane < F) ? sum : -INFINITY;
        float m = v;
#pragma unroll
        for (int off = 32; off; off >>= 1) m = fmaxf(m, __shfl_xor(m, off));
        float e = (lane < F) ? expf(v - m) : 0.f;
        float s2 = e;
#pragma unroll
        for (int off = 32; off; off >>= 1) s2 += __shfl_xor(s2, off);
        float ls = logf(s2);
        if (lane < F) out[(size_t)row * F + lane] = v - m - ls;
    } else {
        if (lane < F) out[(size_t)row * F + lane] = sum;
    }
}

extern "C" void kernel_launch(void* const* d_in, const int* in_sizes, int n_in,
                              void* d_out, int out_size, void* d_ws, size_t ws_size,
                              hipStream_t stream) {
    const float* x  = (const float*)d_in[0];
    const int*   ei = (const int*)  d_in[1];
    const float* ew = (const float*)d_in[2];
    const float* W0 = (const float*)d_in[3];
    const float* b0 = (const float*)d_in[4];
    const float* W1 = (const float*)d_in[5];
    const float* b1 = (const float*)d_in[6];
    const float* W2 = (const float*)d_in[7];
    const float* b2 = (const float*)d_in[8];

    const int E   = in_sizes[2];            // 1600000
    const int H   = in_sizes[4];            // 64
    const int Fin = in_sizes[3] / H;        // 256
    const int N   = in_sizes[0] / Fin;      // 100000
    (void)n_in; (void)out_size; (void)ws_size;

    const int* srcv = ei;                   // edge_index[0]
    const int* dstv = ei + E;               // edge_index[1]

    // ---- workspace layout ----
    float* ws = (float*)d_ws;
    size_t o = 0;
    auto alloc = [&](size_t cnt_) { size_t p = o; o += (cnt_ + 63) & ~(size_t)63; return p; };
    float* dis   = ws + alloc(N);
    float* bufB  = ws + alloc((size_t)N * 64);               // agg out (fp32 trunk)
    unsigned short* hB = (unsigned short*)(ws + alloc((size_t)N * 32));  // bf16 h
    unsigned long long* pairP = (unsigned long long*)(ws + alloc((size_t)E * 2));
    int*   rowptr= (int*)(ws + alloc(N + 1));
    int*   cnt   = (int*)(ws + alloc(N));
    int*   pos   = (int*)(ws + alloc(E));
    int*   bsum  = (int*)(ws + alloc(512));
    int*   boff  = (int*)(ws + alloc(512));
    float* outf  = (float*)d_out;                            // N*40

    const int TB  = 256;
    const int nb1 = (N + 255) / 256;                 // scan blocks (391 <= 512)
    const int ntiles = (N + 63) / 64;                // 1563 gemm tiles
    const int XB  = 1024;                            // cnt blocks

    // ---- fused interleaved: gemm L0 || counting histogram ----
    (void)hipMemsetAsync(cnt, 0, (size_t)N * sizeof(int), stream);
    {
        const int m = (ntiles < XB) ? ntiles : XB;
        const int grid = 2 * m + ((ntiles > XB) ? (ntiles - XB) : (XB - ntiles));
        k_gemm_cnt<256, 64, false><<<grid, TB, 0, stream>>>(
            x, W0, hB, N, ntiles, XB, dstv, cnt, pos, E);
    }

    // ---- scan cnt -> rowptr ----
    k_scan1<<<nb1, 256, 0, stream>>>(cnt, rowptr, bsum, N);
    k_scan2<<<1, 512, 0, stream>>>(bsum, boff, nb1);
    k_scan3<<<(N + TB - 1) / TB, TB, 0, stream>>>(rowptr, boff, N, E);

    // ---- place packed pairs (no atomic) ----
    k_place<<<(E + TB - 1) / TB, TB, 0, stream>>>(srcv, dstv, ew, rowptr, pos, pairP, E);

    // ---- dis + norm over CSR ----
    k_deg_dis <<<(N + TB - 1) / TB, TB, 0, stream>>>(pairP, rowptr, dis, N);
    k_norm_csr<<<(N + TB - 1) / TB, TB, 0, stream>>>(pairP, rowptr, dis, N);

    const int aggGrid = (N * 64 + TB - 1) / TB;      // one wave per node

    // ---- layer 0 aggregate (bf16 gather) ----
    k_node_agg<64, false><<<aggGrid, TB, 0, stream>>>(hB, dis, b0, rowptr, pairP, bufB, N);

    // ---- layer 1: 64 -> 64 (relu on load) ----
    k_gemm<64, 64, true><<<ntiles, TB, 0, stream>>>(bufB, W1, hB, N);
    k_node_agg<64, false><<<aggGrid, TB, 0, stream>>>(hB, dis, b1, rowptr, pairP, bufB, N);

    // ---- layer 2: 64 -> 40, aggregate + fused log_softmax into d_out ----
    k_gemm<64, 40, true><<<ntiles, TB, 0, stream>>>(bufB, W2, hB, N);
    k_node_agg<40, true><<<aggGrid, TB, 0, stream>>>(hB, dis, b2, rowptr, pairP, outf, N);
}

// Round 15
// 331.160 us; speedup vs baseline: 12.7684x; 1.0343x over previous
//
#include <hip/hip_runtime.h>
#include <math.h>

// ---------------------------------------------------------------------------
// GCN 3-layer forward for MI355X.
// R5 tiled GEMM / R7 CSR gather / R8 counting-sort build / R11 reg-prefetch
// GEMM / R12 overlap fusion / R13 bf16 gather (349) / R14 interleaved fused
// blocks (342; fused 87us ~= cnt atomic floor + interference).
// R15: kill serial-row-walk inefficiencies:
//   (a) k_deg_dis / k_norm_csr -> WAVE-per-node (coalesced slot reads; the
//       old thread-per-node walk cost a 64B sector per 8B pair, 2 passes);
//   (b) k_node_agg stages 64 pairs/wave into LDS via ONE coalesced 512B load
//       (wave-internal, no barrier) instead of ~deg broadcast VMEM loads.
// ---------------------------------------------------------------------------

__device__ __forceinline__ unsigned short f2bf(float f) {   // RNE fp32->bf16
    unsigned u = __float_as_uint(f);
    u += 0x7FFFu + ((u >> 16) & 1u);
    return (unsigned short)(u >> 16);
}
__device__ __forceinline__ float bf2f(unsigned short h) {
    return __uint_as_float(((unsigned)h) << 16);
}

// ---- exclusive scan over cnt[N] -> rowptr, 3 kernels ----
__global__ void k_scan1(const int* __restrict__ cnt, int* __restrict__ excl,
                        int* __restrict__ bsum, int n) {
    __shared__ int sm[256];
    int tid = threadIdx.x;
    int i = blockIdx.x * 256 + tid;
    int v = (i < n) ? cnt[i] : 0;
    sm[tid] = v;
    __syncthreads();
    for (int off = 1; off < 256; off <<= 1) {
        int t = (tid >= off) ? sm[tid - off] : 0;
        __syncthreads();
        sm[tid] += t;
        __syncthreads();
    }
    if (i < n) excl[i] = sm[tid] - v;
    if (tid == 255) bsum[blockIdx.x] = sm[255];
}

__global__ void k_scan2(const int* __restrict__ bsum, int* __restrict__ boff, int nb) {
    __shared__ int sm[512];
    int tid = threadIdx.x;
    int v = (tid < nb) ? bsum[tid] : 0;
    sm[tid] = v;
    __syncthreads();
    for (int off = 1; off < 512; off <<= 1) {
        int t = (tid >= off) ? sm[tid - off] : 0;
        __syncthreads();
        sm[tid] += t;
        __syncthreads();
    }
    boff[tid] = sm[tid] - v;   // exclusive
}

__global__ void k_scan3(int* __restrict__ rowptr, const int* __restrict__ boff,
                        int n, int E) {
    int i = blockIdx.x * blockDim.x + threadIdx.x;
    if (i < n) rowptr[i] += boff[i >> 8];
    if (i == 0) rowptr[n] = E;
}

// Place edges into dst-grouped slots (NO atomic): 8B packed {src, ew}.
__global__ void k_place(const int* __restrict__ src, const int* __restrict__ dst,
                        const float* __restrict__ ew, const int* __restrict__ rowptr,
                        const int* __restrict__ pos, unsigned long long* __restrict__ pairP,
                        int E) {
    int e = blockIdx.x * blockDim.x + threadIdx.x;
    if (e < E) {
        int d = dst[e];
        int p = rowptr[d] + pos[e];
        unsigned long long pk = (unsigned long long)__float_as_uint(ew[e]) << 32
                              | (unsigned int)src[e];
        pairP[p] = pk;
    }
}

// Wave-per-node: dis = rsqrt(1 + sum ew). Coalesced 64-slot reads + shuffle
// reduce (old thread-per-node walk: 64B sector per 8B pair).
__global__ __launch_bounds__(256) void k_deg_dis(
    const unsigned long long* __restrict__ pairP,
    const int* __restrict__ rowptr, float* __restrict__ dis, int n)
{
    const int lane = threadIdx.x & 63;
    int row = (int)((blockIdx.x * blockDim.x + threadIdx.x) >> 6);
    if (row >= n) return;
    row = __builtin_amdgcn_readfirstlane(row);
    const int a = rowptr[row], b = rowptr[row + 1];
    float s = 0.f;
    for (int idx = a + lane; idx < b; idx += 64)
        s += __uint_as_float((unsigned int)(pairP[idx] >> 32));
#pragma unroll
    for (int off = 32; off; off >>= 1) s += __shfl_xor(s, off);
    if (lane == 0) {
        float d = 1.0f + s;   // self-loop
        dis[row] = (d > 0.f) ? rsqrtf(d) : 0.f;
    }
}

// Wave-per-node: rewrite payload ew -> nrm = dis[s]*ew*dis[d], lane-parallel
// coalesced read+write.
__global__ __launch_bounds__(256) void k_norm_csr(
    unsigned long long* __restrict__ pairP, const int* __restrict__ rowptr,
    const float* __restrict__ dis, int n)
{
    const int lane = threadIdx.x & 63;
    int row = (int)((blockIdx.x * blockDim.x + threadIdx.x) >> 6);
    if (row >= n) return;
    row = __builtin_amdgcn_readfirstlane(row);
    const int a = rowptr[row], b = rowptr[row + 1];
    const float dd = dis[row];
    for (int idx = a + lane; idx < b; idx += 64) {
        unsigned long long pk = pairP[idx];
        int s = (int)(unsigned int)pk;
        float w = __uint_as_float((unsigned int)(pk >> 32));
        float nrm = dis[s] * w * dd;
        pairP[idx] = ((unsigned long long)__float_as_uint(nrm) << 32) | (unsigned int)s;
    }
}

// Tiled GEMM body: HB(bf16) = act(X fp32)@W, BM64xBN64xBK32, 4x4 reg tile,
// reg-prefetch of tile t+1, T-loop NOT unrolled (R9 lesson).
template<int K, int NOUT, bool RELU_IN>
__device__ __forceinline__ void gemm_tile_body(
    const float* __restrict__ X, const float* __restrict__ W,
    unsigned short* __restrict__ HB, int nrows, int tile)
{
    constexpr int BM = 64, BN = 64, BK = 32;
    constexpr int T  = K / BK;
    __shared__ float As[BK][BM + 4];   // As[k][m]
    __shared__ float Bs[BK][BN + 4];

    const int tid = (int)threadIdx.x;
    const int tx  = tid & 15;          // cols tx*4..+3
    const int ty  = tid >> 4;          // rows ty*4..+3
    const int r0  = tile * BM;

    const int ar = tid >> 3;           // 0..31, rows ar and ar+32
    const int aq = tid & 7;            // float4 index in k-dir
    const int bk = tid >> 4;           // 0..15, k-rows bk and bk+16
    const int bc = tid & 15;           // float4 index in n-dir

    const int rowA0 = min(r0 + ar,      nrows - 1);
    const int rowA1 = min(r0 + ar + 32, nrows - 1);
    const float* pA0 = X + (size_t)rowA0 * K + aq * 4;
    const float* pA1 = X + (size_t)rowA1 * K + aq * 4;
    const bool wok = (bc * 4 + 3 < NOUT);   // W guard (NOUT=40 case)
    const float* pB0 = W + (size_t)bk * NOUT + bc * 4;
    const float* pB1 = W + (size_t)(bk + 16) * NOUT + bc * 4;
    const float4 z4 = make_float4(0.f, 0.f, 0.f, 0.f);

    float4 ra0, ra1, rb0, rb1;
    ra0 = *(const float4*)pA0;
    ra1 = *(const float4*)pA1;
    rb0 = wok ? *(const float4*)pB0 : z4;
    rb1 = wok ? *(const float4*)pB1 : z4;

    float acc[4][4] = {};

#pragma unroll 1
    for (int t = 0; t < T; ++t) {
        if (RELU_IN) {
            ra0.x = fmaxf(ra0.x, 0.f); ra0.y = fmaxf(ra0.y, 0.f);
            ra0.z = fmaxf(ra0.z, 0.f); ra0.w = fmaxf(ra0.w, 0.f);
            ra1.x = fmaxf(ra1.x, 0.f); ra1.y = fmaxf(ra1.y, 0.f);
            ra1.z = fmaxf(ra1.z, 0.f); ra1.w = fmaxf(ra1.w, 0.f);
        }
        As[aq * 4 + 0][ar]      = ra0.x;
        As[aq * 4 + 1][ar]      = ra0.y;
        As[aq * 4 + 2][ar]      = ra0.z;
        As[aq * 4 + 3][ar]      = ra0.w;
        As[aq * 4 + 0][ar + 32] = ra1.x;
        As[aq * 4 + 1][ar + 32] = ra1.y;
        As[aq * 4 + 2][ar + 32] = ra1.z;
        As[aq * 4 + 3][ar + 32] = ra1.w;
        *(float4*)&Bs[bk][bc * 4]      = rb0;
        *(float4*)&Bs[bk + 16][bc * 4] = rb1;
        __syncthreads();

        if (t + 1 < T) {
            const int ko = (t + 1) * BK;
            ra0 = *(const float4*)(pA0 + ko);
            ra1 = *(const float4*)(pA1 + ko);
            rb0 = wok ? *(const float4*)(pB0 + (size_t)ko * NOUT) : z4;
            rb1 = wok ? *(const float4*)(pB1 + (size_t)ko * NOUT) : z4;
        }

#pragma unroll
        for (int kk = 0; kk < BK; ++kk) {
            float4 a = *(const float4*)&As[kk][ty * 4];
            float4 b = *(const float4*)&Bs[kk][tx * 4];
            acc[0][0] += a.x * b.x; acc[0][1] += a.x * b.y; acc[0][2] += a.x * b.z; acc[0][3] += a.x * b.w;
            acc[1][0] += a.y * b.x; acc[1][1] += a.y * b.y; acc[1][2] += a.y * b.z; acc[1][3] += a.y * b.w;
            acc[2][0] += a.z * b.x; acc[2][1] += a.z * b.y; acc[2][2] += a.z * b.z; acc[2][3] += a.z * b.w;
            acc[3][0] += a.w * b.x; acc[3][1] += a.w * b.y; acc[3][2] += a.w * b.z; acc[3][3] += a.w * b.w;
        }
        __syncthreads();
    }

    if (tx * 4 + 3 < NOUT) {
#pragma unroll
        for (int i = 0; i < 4; ++i) {
            int row = r0 + ty * 4 + i;
            if (row < nrows) {
                ushort4 hv;
                hv.x = f2bf(acc[i][0]); hv.y = f2bf(acc[i][1]);
                hv.z = f2bf(acc[i][2]); hv.w = f2bf(acc[i][3]);
                *(ushort4*)&HB[(size_t)row * NOUT + tx * 4] = hv;
            }
        }
    }
}

// Plain GEMM kernel (layers 1 & 2).
template<int K, int NOUT, bool RELU_IN>
__global__ __launch_bounds__(256) void k_gemm(
    const float* __restrict__ X, const float* __restrict__ W,
    unsigned short* __restrict__ HB, int nrows)
{
    gemm_tile_body<K, NOUT, RELU_IN>(X, W, HB, nrows, (int)blockIdx.x);
}

// Fused, INTERLEAVED: paired region [0, 2*min(ntiles,ncnt)): even=cnt,
// odd=gemm; tail = leftover blocks of the larger role.
template<int K, int NOUT, bool RELU_IN>
__global__ __launch_bounds__(256) void k_gemm_cnt(
    const float* __restrict__ X, const float* __restrict__ W,
    unsigned short* __restrict__ HB, int nrows, int ntiles, int ncnt,
    const int* __restrict__ dst, int* __restrict__ cnt, int* __restrict__ pos, int E)
{
    const int b  = (int)blockIdx.x;
    const int m  = min(ntiles, ncnt);
    bool isCnt; int idx;
    if (b < 2 * m) {
        isCnt = ((b & 1) == 0);
        idx   = b >> 1;
    } else {
        int rem = b - 2 * m;
        isCnt = (ncnt > ntiles);
        idx   = m + rem;
    }
    if (!isCnt) {
        gemm_tile_body<K, NOUT, RELU_IN>(X, W, HB, nrows, idx);
    } else {
        int e0     = idx * 256 + (int)threadIdx.x;
        int stride = ncnt * 256;
        for (int e = e0; e < E; e += stride)
            pos[e] = atomicAdd(&cnt[dst[e]], 1);
    }
}

// Gather aggregation: one wave per node, lane = feature. No atomics.
// R15: pairs staged through LDS — one coalesced 512B wave-load per 64 slots
// (wave-internal, compiler inserts lgkmcnt; no barrier), then broadcast reads.
template<int F, bool LSM>
__global__ __launch_bounds__(256) void k_node_agg(
    const unsigned short* __restrict__ hB, const float* __restrict__ dis,
    const float* __restrict__ bias, const int* __restrict__ rowptr,
    const unsigned long long* __restrict__ pairP,
    float* __restrict__ out, int n)
{
    __shared__ unsigned long long pl[4][64];   // 2KB: 64 pairs per wave
    const int lane = threadIdx.x & 63;
    const int wid  = (threadIdx.x >> 6) & 3;
    int row = (int)((blockIdx.x * blockDim.x + threadIdx.x) >> 6);
    if (row >= n) return;
    row = __builtin_amdgcn_readfirstlane(row);   // wave-uniform -> SGPR addrs

    const int a = rowptr[row], b = rowptr[row + 1];
    float d  = dis[row];
    float dd = d * d;
    float sum = 0.f;
    if (lane < F) sum = bf2f(hB[(size_t)row * F + lane]) * dd + bias[lane];

    for (int base = a; base < b; base += 64) {
        int idx = base + lane;
        pl[wid][lane] = (idx < b) ? pairP[idx] : 0ull;   // coalesced 512B
        int c = min(64, b - base);
        int j = 0;
        for (; j + 4 <= c; j += 4) {
            unsigned long long p0 = pl[wid][j],     p1 = pl[wid][j + 1];
            unsigned long long p2 = pl[wid][j + 2], p3 = pl[wid][j + 3];
            int   s0 = (int)(unsigned int)p0, s1 = (int)(unsigned int)p1;
            int   s2 = (int)(unsigned int)p2, s3 = (int)(unsigned int)p3;
            float w0 = __uint_as_float((unsigned int)(p0 >> 32));
            float w1 = __uint_as_float((unsigned int)(p1 >> 32));
            float w2 = __uint_as_float((unsigned int)(p2 >> 32));
            float w3 = __uint_as_float((unsigned int)(p3 >> 32));
            if (lane < F) {
                sum += bf2f(hB[(size_t)s0 * F + lane]) * w0;
                sum += bf2f(hB[(size_t)s1 * F + lane]) * w1;
                sum += bf2f(hB[(size_t)s2 * F + lane]) * w2;
                sum += bf2f(hB[(size_t)s3 * F + lane]) * w3;
            }
        }
        for (; j < c; ++j) {
            unsigned long long p = pl[wid][j];
            int s = (int)(unsigned int)p;
            float w = __uint_as_float((unsigned int)(p >> 32));
            if (lane < F) sum += bf2f(hB[(size_t)s * F + lane]) * w;
        }
    }

    if (LSM) {
        float v = (lane < F) ? sum : -INFINITY;
        float m = v;
#pragma unroll
        for (int off = 32; off; off >>= 1) m = fmaxf(m, __shfl_xor(m, off));
        float e = (lane < F) ? expf(v - m) : 0.f;
        float s2 = e;
#pragma unroll
        for (int off = 32; off; off >>= 1) s2 += __shfl_xor(s2, off);
        float ls = logf(s2);
        if (lane < F) out[(size_t)row * F + lane] = v - m - ls;
    } else {
        if (lane < F) out[(size_t)row * F + lane] = sum;
    }
}

extern "C" void kernel_launch(void* const* d_in, const int* in_sizes, int n_in,
                              void* d_out, int out_size, void* d_ws, size_t ws_size,
                              hipStream_t stream) {
    const float* x  = (const float*)d_in[0];
    const int*   ei = (const int*)  d_in[1];
    const float* ew = (const float*)d_in[2];
    const float* W0 = (const float*)d_in[3];
    const float* b0 = (const float*)d_in[4];
    const float* W1 = (const float*)d_in[5];
    const float* b1 = (const float*)d_in[6];
    const float* W2 = (const float*)d_in[7];
    const float* b2 = (const float*)d_in[8];

    const int E   = in_sizes[2];            // 1600000
    const int H   = in_sizes[4];            // 64
    const int Fin = in_sizes[3] / H;        // 256
    const int N   = in_sizes[0] / Fin;      // 100000
    (void)n_in; (void)out_size; (void)ws_size;

    const int* srcv = ei;                   // edge_index[0]
    const int* dstv = ei + E;               // edge_index[1]

    // ---- workspace layout ----
    float* ws = (float*)d_ws;
    size_t o = 0;
    auto alloc = [&](size_t cnt_) { size_t p = o; o += (cnt_ + 63) & ~(size_t)63; return p; };
    float* dis   = ws + alloc(N);
    float* bufB  = ws + alloc((size_t)N * 64);               // agg out (fp32 trunk)
    unsigned short* hB = (unsigned short*)(ws + alloc((size_t)N * 32));  // bf16 h
    unsigned long long* pairP = (unsigned long long*)(ws + alloc((size_t)E * 2));
    int*   rowptr= (int*)(ws + alloc(N + 1));
    int*   cnt   = (int*)(ws + alloc(N));
    int*   pos   = (int*)(ws + alloc(E));
    int*   bsum  = (int*)(ws + alloc(512));
    int*   boff  = (int*)(ws + alloc(512));
    float* outf  = (float*)d_out;                            // N*40

    const int TB  = 256;
    const int nb1 = (N + 255) / 256;                 // scan blocks (391 <= 512)
    const int ntiles = (N + 63) / 64;                // 1563 gemm tiles
    const int XB  = 1024;                            // cnt blocks

    // ---- fused interleaved: gemm L0 || counting histogram ----
    (void)hipMemsetAsync(cnt, 0, (size_t)N * sizeof(int), stream);
    {
        const int m = (ntiles < XB) ? ntiles : XB;
        const int grid = 2 * m + ((ntiles > XB) ? (ntiles - XB) : (XB - ntiles));
        k_gemm_cnt<256, 64, false><<<grid, TB, 0, stream>>>(
            x, W0, hB, N, ntiles, XB, dstv, cnt, pos, E);
    }

    // ---- scan cnt -> rowptr ----
    k_scan1<<<nb1, 256, 0, stream>>>(cnt, rowptr, bsum, N);
    k_scan2<<<1, 512, 0, stream>>>(bsum, boff, nb1);
    k_scan3<<<(N + TB - 1) / TB, TB, 0, stream>>>(rowptr, boff, N, E);

    // ---- place packed pairs (no atomic) ----
    k_place<<<(E + TB - 1) / TB, TB, 0, stream>>>(srcv, dstv, ew, rowptr, pos, pairP, E);

    const int aggGrid = (N * 64 + TB - 1) / TB;      // one wave per node

    // ---- dis + norm over CSR (wave-per-node, coalesced) ----
    k_deg_dis <<<aggGrid, TB, 0, stream>>>(pairP, rowptr, dis, N);
    k_norm_csr<<<aggGrid, TB, 0, stream>>>(pairP, rowptr, dis, N);

    // ---- layer 0 aggregate (bf16 gather) ----
    k_node_agg<64, false><<<aggGrid, TB, 0, stream>>>(hB, dis, b0, rowptr, pairP, bufB, N);

    // ---- layer 1: 64 -> 64 (relu on load) ----
    k_gemm<64, 64, true><<<ntiles, TB, 0, stream>>>(bufB, W1, hB, N);
    k_node_agg<64, false><<<aggGrid, TB, 0, stream>>>(hB, dis, b1, rowptr, pairP, bufB, N);

    // ---- layer 2: 64 -> 40, aggregate + fused log_softmax into d_out ----
    k_gemm<64, 40, true><<<ntiles, TB, 0, stream>>>(bufB, W2, hB, N);
    k_node_agg<40, true><<<aggGrid, TB, 0, stream>>>(hB, dis, b2, rowptr, pairP, outf, N);
}

// Round 16
// 321.276 us; speedup vs baseline: 13.1612x; 1.0308x over previous
//
#include <hip/hip_runtime.h>
#include <math.h>

// ---------------------------------------------------------------------------
// GCN 3-layer forward for MI355X.
// R5 tiled GEMM / R7 CSR gather / R8 counting-sort build / R11 reg-prefetch
// GEMM / R12 overlap fusion / R13 bf16 gather (349) / R14 interleave (342)
// / R15 wave-per-node deg/norm + LDS pair staging (331).
// R16: (a) cnt role needs only ~32K threads to saturate TCC atomics (23G/s
//   throughput-bound, ~9K outstanding suffices) -> XB 1024->256 so cnt takes
//   ~1 slot/CU and gemm-L0 rides in the other ~7 (was: 4 slots wasted, gemm
//   tail ran after the 70us atomic window);
//   (b) L1/L2 GEMMs persistent (512 blocks grid-stride over tiles): W stays
//   L2-hot per CU, dispatch ramp amortized.
// ---------------------------------------------------------------------------

__device__ __forceinline__ unsigned short f2bf(float f) {   // RNE fp32->bf16
    unsigned u = __float_as_uint(f);
    u += 0x7FFFu + ((u >> 16) & 1u);
    return (unsigned short)(u >> 16);
}
__device__ __forceinline__ float bf2f(unsigned short h) {
    return __uint_as_float(((unsigned)h) << 16);
}

// ---- exclusive scan over cnt[N] -> rowptr, 3 kernels ----
__global__ void k_scan1(const int* __restrict__ cnt, int* __restrict__ excl,
                        int* __restrict__ bsum, int n) {
    __shared__ int sm[256];
    int tid = threadIdx.x;
    int i = blockIdx.x * 256 + tid;
    int v = (i < n) ? cnt[i] : 0;
    sm[tid] = v;
    __syncthreads();
    for (int off = 1; off < 256; off <<= 1) {
        int t = (tid >= off) ? sm[tid - off] : 0;
        __syncthreads();
        sm[tid] += t;
        __syncthreads();
    }
    if (i < n) excl[i] = sm[tid] - v;
    if (tid == 255) bsum[blockIdx.x] = sm[255];
}

__global__ void k_scan2(const int* __restrict__ bsum, int* __restrict__ boff, int nb) {
    __shared__ int sm[512];
    int tid = threadIdx.x;
    int v = (tid < nb) ? bsum[tid] : 0;
    sm[tid] = v;
    __syncthreads();
    for (int off = 1; off < 512; off <<= 1) {
        int t = (tid >= off) ? sm[tid - off] : 0;
        __syncthreads();
        sm[tid] += t;
        __syncthreads();
    }
    boff[tid] = sm[tid] - v;   // exclusive
}

__global__ void k_scan3(int* __restrict__ rowptr, const int* __restrict__ boff,
                        int n, int E) {
    int i = blockIdx.x * blockDim.x + threadIdx.x;
    if (i < n) rowptr[i] += boff[i >> 8];
    if (i == 0) rowptr[n] = E;
}

// Place edges into dst-grouped slots (NO atomic): 8B packed {src, ew}.
__global__ void k_place(const int* __restrict__ src, const int* __restrict__ dst,
                        const float* __restrict__ ew, const int* __restrict__ rowptr,
                        const int* __restrict__ pos, unsigned long long* __restrict__ pairP,
                        int E) {
    int e = blockIdx.x * blockDim.x + threadIdx.x;
    if (e < E) {
        int d = dst[e];
        int p = rowptr[d] + pos[e];
        unsigned long long pk = (unsigned long long)__float_as_uint(ew[e]) << 32
                              | (unsigned int)src[e];
        pairP[p] = pk;
    }
}

// Wave-per-node: dis = rsqrt(1 + sum ew). Coalesced 64-slot reads + shuffle.
__global__ __launch_bounds__(256) void k_deg_dis(
    const unsigned long long* __restrict__ pairP,
    const int* __restrict__ rowptr, float* __restrict__ dis, int n)
{
    const int lane = threadIdx.x & 63;
    int row = (int)((blockIdx.x * blockDim.x + threadIdx.x) >> 6);
    if (row >= n) return;
    row = __builtin_amdgcn_readfirstlane(row);
    const int a = rowptr[row], b = rowptr[row + 1];
    float s = 0.f;
    for (int idx = a + lane; idx < b; idx += 64)
        s += __uint_as_float((unsigned int)(pairP[idx] >> 32));
#pragma unroll
    for (int off = 32; off; off >>= 1) s += __shfl_xor(s, off);
    if (lane == 0) {
        float d = 1.0f + s;   // self-loop
        dis[row] = (d > 0.f) ? rsqrtf(d) : 0.f;
    }
}

// Wave-per-node: rewrite payload ew -> nrm = dis[s]*ew*dis[d], lane-parallel.
__global__ __launch_bounds__(256) void k_norm_csr(
    unsigned long long* __restrict__ pairP, const int* __restrict__ rowptr,
    const float* __restrict__ dis, int n)
{
    const int lane = threadIdx.x & 63;
    int row = (int)((blockIdx.x * blockDim.x + threadIdx.x) >> 6);
    if (row >= n) return;
    row = __builtin_amdgcn_readfirstlane(row);
    const int a = rowptr[row], b = rowptr[row + 1];
    const float dd = dis[row];
    for (int idx = a + lane; idx < b; idx += 64) {
        unsigned long long pk = pairP[idx];
        int s = (int)(unsigned int)pk;
        float w = __uint_as_float((unsigned int)(pk >> 32));
        float nrm = dis[s] * w * dd;
        pairP[idx] = ((unsigned long long)__float_as_uint(nrm) << 32) | (unsigned int)s;
    }
}

// Tiled GEMM body: HB(bf16) = act(X fp32)@W, BM64xBN64xBK32, 4x4 reg tile,
// reg-prefetch of tile t+1, T-loop NOT unrolled (R9 lesson).
template<int K, int NOUT, bool RELU_IN>
__device__ __forceinline__ void gemm_tile_body(
    const float* __restrict__ X, const float* __restrict__ W,
    unsigned short* __restrict__ HB, int nrows, int tile)
{
    constexpr int BM = 64, BN = 64, BK = 32;
    constexpr int T  = K / BK;
    __shared__ float As[BK][BM + 4];   // As[k][m]
    __shared__ float Bs[BK][BN + 4];

    const int tid = (int)threadIdx.x;
    const int tx  = tid & 15;          // cols tx*4..+3
    const int ty  = tid >> 4;          // rows ty*4..+3
    const int r0  = tile * BM;

    const int ar = tid >> 3;           // 0..31, rows ar and ar+32
    const int aq = tid & 7;            // float4 index in k-dir
    const int bk = tid >> 4;           // 0..15, k-rows bk and bk+16
    const int bc = tid & 15;           // float4 index in n-dir

    const int rowA0 = min(r0 + ar,      nrows - 1);
    const int rowA1 = min(r0 + ar + 32, nrows - 1);
    const float* pA0 = X + (size_t)rowA0 * K + aq * 4;
    const float* pA1 = X + (size_t)rowA1 * K + aq * 4;
    const bool wok = (bc * 4 + 3 < NOUT);   // W guard (NOUT=40 case)
    const float* pB0 = W + (size_t)bk * NOUT + bc * 4;
    const float* pB1 = W + (size_t)(bk + 16) * NOUT + bc * 4;
    const float4 z4 = make_float4(0.f, 0.f, 0.f, 0.f);

    float4 ra0, ra1, rb0, rb1;
    ra0 = *(const float4*)pA0;
    ra1 = *(const float4*)pA1;
    rb0 = wok ? *(const float4*)pB0 : z4;
    rb1 = wok ? *(const float4*)pB1 : z4;

    float acc[4][4] = {};

#pragma unroll 1
    for (int t = 0; t < T; ++t) {
        if (RELU_IN) {
            ra0.x = fmaxf(ra0.x, 0.f); ra0.y = fmaxf(ra0.y, 0.f);
            ra0.z = fmaxf(ra0.z, 0.f); ra0.w = fmaxf(ra0.w, 0.f);
            ra1.x = fmaxf(ra1.x, 0.f); ra1.y = fmaxf(ra1.y, 0.f);
            ra1.z = fmaxf(ra1.z, 0.f); ra1.w = fmaxf(ra1.w, 0.f);
        }
        As[aq * 4 + 0][ar]      = ra0.x;
        As[aq * 4 + 1][ar]      = ra0.y;
        As[aq * 4 + 2][ar]      = ra0.z;
        As[aq * 4 + 3][ar]      = ra0.w;
        As[aq * 4 + 0][ar + 32] = ra1.x;
        As[aq * 4 + 1][ar + 32] = ra1.y;
        As[aq * 4 + 2][ar + 32] = ra1.z;
        As[aq * 4 + 3][ar + 32] = ra1.w;
        *(float4*)&Bs[bk][bc * 4]      = rb0;
        *(float4*)&Bs[bk + 16][bc * 4] = rb1;
        __syncthreads();

        if (t + 1 < T) {
            const int ko = (t + 1) * BK;
            ra0 = *(const float4*)(pA0 + ko);
            ra1 = *(const float4*)(pA1 + ko);
            rb0 = wok ? *(const float4*)(pB0 + (size_t)ko * NOUT) : z4;
            rb1 = wok ? *(const float4*)(pB1 + (size_t)ko * NOUT) : z4;
        }

#pragma unroll
        for (int kk = 0; kk < BK; ++kk) {
            float4 a = *(const float4*)&As[kk][ty * 4];
            float4 b = *(const float4*)&Bs[kk][tx * 4];
            acc[0][0] += a.x * b.x; acc[0][1] += a.x * b.y; acc[0][2] += a.x * b.z; acc[0][3] += a.x * b.w;
            acc[1][0] += a.y * b.x; acc[1][1] += a.y * b.y; acc[1][2] += a.y * b.z; acc[1][3] += a.y * b.w;
            acc[2][0] += a.z * b.x; acc[2][1] += a.z * b.y; acc[2][2] += a.z * b.z; acc[2][3] += a.z * b.w;
            acc[3][0] += a.w * b.x; acc[3][1] += a.w * b.y; acc[3][2] += a.w * b.z; acc[3][3] += a.w * b.w;
        }
        __syncthreads();
    }

    if (tx * 4 + 3 < NOUT) {
#pragma unroll
        for (int i = 0; i < 4; ++i) {
            int row = r0 + ty * 4 + i;
            if (row < nrows) {
                ushort4 hv;
                hv.x = f2bf(acc[i][0]); hv.y = f2bf(acc[i][1]);
                hv.z = f2bf(acc[i][2]); hv.w = f2bf(acc[i][3]);
                *(ushort4*)&HB[(size_t)row * NOUT + tx * 4] = hv;
            }
        }
    }
}

// Persistent GEMM (layers 1 & 2): grid-stride over row tiles; W stays L2-hot.
template<int K, int NOUT, bool RELU_IN>
__global__ __launch_bounds__(256) void k_gemm(
    const float* __restrict__ X, const float* __restrict__ W,
    unsigned short* __restrict__ HB, int nrows, int ntiles)
{
#pragma unroll 1
    for (int tile = (int)blockIdx.x; tile < ntiles; tile += (int)gridDim.x)
        gemm_tile_body<K, NOUT, RELU_IN>(X, W, HB, nrows, tile);
}

// Fused, INTERLEAVED: paired region [0, 2*min(ntiles,ncnt)): even=cnt,
// odd=gemm; tail = leftover blocks of the larger role.
template<int K, int NOUT, bool RELU_IN>
__global__ __launch_bounds__(256) void k_gemm_cnt(
    const float* __restrict__ X, const float* __restrict__ W,
    unsigned short* __restrict__ HB, int nrows, int ntiles, int ncnt,
    const int* __restrict__ dst, int* __restrict__ cnt, int* __restrict__ pos, int E)
{
    const int b  = (int)blockIdx.x;
    const int m  = min(ntiles, ncnt);
    bool isCnt; int idx;
    if (b < 2 * m) {
        isCnt = ((b & 1) == 0);
        idx   = b >> 1;
    } else {
        int rem = b - 2 * m;
        isCnt = (ncnt > ntiles);
        idx   = m + rem;
    }
    if (!isCnt) {
        gemm_tile_body<K, NOUT, RELU_IN>(X, W, HB, nrows, idx);
    } else {
        int e0     = idx * 256 + (int)threadIdx.x;
        int stride = ncnt * 256;
        for (int e = e0; e < E; e += stride)
            pos[e] = atomicAdd(&cnt[dst[e]], 1);
    }
}

// Gather aggregation: one wave per node, lane = feature. No atomics.
// Pairs staged via ONE coalesced 512B wave-load per 64 slots.
template<int F, bool LSM>
__global__ __launch_bounds__(256) void k_node_agg(
    const unsigned short* __restrict__ hB, const float* __restrict__ dis,
    const float* __restrict__ bias, const int* __restrict__ rowptr,
    const unsigned long long* __restrict__ pairP,
    float* __restrict__ out, int n)
{
    __shared__ unsigned long long pl[4][64];   // 2KB: 64 pairs per wave
    const int lane = threadIdx.x & 63;
    const int wid  = (threadIdx.x >> 6) & 3;
    int row = (int)((blockIdx.x * blockDim.x + threadIdx.x) >> 6);
    if (row >= n) return;
    row = __builtin_amdgcn_readfirstlane(row);   // wave-uniform -> SGPR addrs

    const int a = rowptr[row], b = rowptr[row + 1];
    float d  = dis[row];
    float dd = d * d;
    float sum = 0.f;
    if (lane < F) sum = bf2f(hB[(size_t)row * F + lane]) * dd + bias[lane];

    for (int base = a; base < b; base += 64) {
        int idx = base + lane;
        pl[wid][lane] = (idx < b) ? pairP[idx] : 0ull;   // coalesced 512B
        int c = min(64, b - base);
        int j = 0;
        for (; j + 4 <= c; j += 4) {
            unsigned long long p0 = pl[wid][j],     p1 = pl[wid][j + 1];
            unsigned long long p2 = pl[wid][j + 2], p3 = pl[wid][j + 3];
            int   s0 = (int)(unsigned int)p0, s1 = (int)(unsigned int)p1;
            int   s2 = (int)(unsigned int)p2, s3 = (int)(unsigned int)p3;
            float w0 = __uint_as_float((unsigned int)(p0 >> 32));
            float w1 = __uint_as_float((unsigned int)(p1 >> 32));
            float w2 = __uint_as_float((unsigned int)(p2 >> 32));
            float w3 = __uint_as_float((unsigned int)(p3 >> 32));
            if (lane < F) {
                sum += bf2f(hB[(size_t)s0 * F + lane]) * w0;
                sum += bf2f(hB[(size_t)s1 * F + lane]) * w1;
                sum += bf2f(hB[(size_t)s2 * F + lane]) * w2;
                sum += bf2f(hB[(size_t)s3 * F + lane]) * w3;
            }
        }
        for (; j < c; ++j) {
            unsigned long long p = pl[wid][j];
            int s = (int)(unsigned int)p;
            float w = __uint_as_float((unsigned int)(p >> 32));
            if (lane < F) sum += bf2f(hB[(size_t)s * F + lane]) * w;
        }
    }

    if (LSM) {
        float v = (lane < F) ? sum : -INFINITY;
        float m = v;
#pragma unroll
        for (int off = 32; off; off >>= 1) m = fmaxf(m, __shfl_xor(m, off));
        float e = (lane < F) ? expf(v - m) : 0.f;
        float s2 = e;
#pragma unroll
        for (int off = 32; off; off >>= 1) s2 += __shfl_xor(s2, off);
        float ls = logf(s2);
        if (lane < F) out[(size_t)row * F + lane] = v - m - ls;
    } else {
        if (lane < F) out[(size_t)row * F + lane] = sum;
    }
}

extern "C" void kernel_launch(void* const* d_in, const int* in_sizes, int n_in,
                              void* d_out, int out_size, void* d_ws, size_t ws_size,
                              hipStream_t stream) {
    const float* x  = (const float*)d_in[0];
    const int*   ei = (const int*)  d_in[1];
    const float* ew = (const float*)d_in[2];
    const float* W0 = (const float*)d_in[3];
    const float* b0 = (const float*)d_in[4];
    const float* W1 = (const float*)d_in[5];
    const float* b1 = (const float*)d_in[6];
    const float* W2 = (const float*)d_in[7];
    const float* b2 = (const float*)d_in[8];

    const int E   = in_sizes[2];            // 1600000
    const int H   = in_sizes[4];            // 64
    const int Fin = in_sizes[3] / H;        // 256
    const int N   = in_sizes[0] / Fin;      // 100000
    (void)n_in; (void)out_size; (void)ws_size;

    const int* srcv = ei;                   // edge_index[0]
    const int* dstv = ei + E;               // edge_index[1]

    // ---- workspace layout ----
    float* ws = (float*)d_ws;
    size_t o = 0;
    auto alloc = [&](size_t cnt_) { size_t p = o; o += (cnt_ + 63) & ~(size_t)63; return p; };
    float* dis   = ws + alloc(N);
    float* bufB  = ws + alloc((size_t)N * 64);               // agg out (fp32 trunk)
    unsigned short* hB = (unsigned short*)(ws + alloc((size_t)N * 32));  // bf16 h
    unsigned long long* pairP = (unsigned long long*)(ws + alloc((size_t)E * 2));
    int*   rowptr= (int*)(ws + alloc(N + 1));
    int*   cnt   = (int*)(ws + alloc(N));
    int*   pos   = (int*)(ws + alloc(E));
    int*   bsum  = (int*)(ws + alloc(512));
    int*   boff  = (int*)(ws + alloc(512));
    float* outf  = (float*)d_out;                            // N*40

    const int TB  = 256;
    const int nb1 = (N + 255) / 256;                 // scan blocks (391 <= 512)
    const int ntiles = (N + 63) / 64;                // 1563 gemm tiles
    const int XB  = 256;                             // cnt blocks (R16: 1024->256)

    // ---- fused interleaved: gemm L0 || counting histogram ----
    (void)hipMemsetAsync(cnt, 0, (size_t)N * sizeof(int), stream);
    {
        const int m = (ntiles < XB) ? ntiles : XB;
        const int grid = 2 * m + ((ntiles > XB) ? (ntiles - XB) : (XB - ntiles));
        k_gemm_cnt<256, 64, false><<<grid, TB, 0, stream>>>(
            x, W0, hB, N, ntiles, XB, dstv, cnt, pos, E);
    }

    // ---- scan cnt -> rowptr ----
    k_scan1<<<nb1, 256, 0, stream>>>(cnt, rowptr, bsum, N);
    k_scan2<<<1, 512, 0, stream>>>(bsum, boff, nb1);
    k_scan3<<<(N + TB - 1) / TB, TB, 0, stream>>>(rowptr, boff, N, E);

    // ---- place packed pairs (no atomic) ----
    k_place<<<(E + TB - 1) / TB, TB, 0, stream>>>(srcv, dstv, ew, rowptr, pos, pairP, E);

    const int aggGrid = (N * 64 + TB - 1) / TB;      // one wave per node

    // ---- dis + norm over CSR (wave-per-node, coalesced) ----
    k_deg_dis <<<aggGrid, TB, 0, stream>>>(pairP, rowptr, dis, N);
    k_norm_csr<<<aggGrid, TB, 0, stream>>>(pairP, rowptr, dis, N);

    // ---- layer 0 aggregate (bf16 gather) ----
    k_node_agg<64, false><<<aggGrid, TB, 0, stream>>>(hB, dis, b0, rowptr, pairP, bufB, N);

    // ---- layer 1: 64 -> 64 (relu on load), persistent grid ----
    k_gemm<64, 64, true><<<512, TB, 0, stream>>>(bufB, W1, hB, N, ntiles);
    k_node_agg<64, false><<<aggGrid, TB, 0, stream>>>(hB, dis, b1, rowptr, pairP, bufB, N);

    // ---- layer 2: 64 -> 40, aggregate + fused log_softmax into d_out ----
    k_gemm<64, 40, true><<<512, TB, 0, stream>>>(bufB, W2, hB, N, ntiles);
    k_node_agg<40, true><<<aggGrid, TB, 0, stream>>>(hB, dis, b2, rowptr, pairP, outf, N);
}